// Round 18
// baseline (149.938 us; speedup 1.0000x reference)
//
#include <hip/hip_runtime.h>
#include <hip/hip_bf16.h>

typedef __bf16 bf16x8 __attribute__((ext_vector_type(8)));
typedef __bf16 bf16x4 __attribute__((ext_vector_type(4)));
typedef float f32x4 __attribute__((ext_vector_type(4)));

#define SEQ   2048
#define NB    2
#define NTOK  4096
#define HIDD  512
#define NHEAD 16
#define DHEAD 64
#define QKVN  3072
#define GUN   2048

// workspace layout (bytes)
#define OFF_WQKVT  0u
#define OFF_WOT    3145728u
#define OFF_WGUT   4194304u
#define OFF_WDT    6291456u
#define OFF_HB     7340032u
#define OFF_QB     11534336u                  // qb [4096][1024] bf16
#define OFF_KB     (OFF_QB + 8388608u)        // kb [32][2048][64] bf16
#define OFF_VB     (OFF_QB + 16777216u)       // vb (dead after kvprep -> mb)
#define OFF_ATTN   36700160u
#define OFF_H2     45088768u                  // vtb during attn; h2b bf16 after
#define OFF_G      53477376u
#define OFF_M      OFF_VB

#define QSCALE 0.1803368801111731f            // 0.125 * log2(e)

#if __has_builtin(__builtin_amdgcn_exp2f)
#define EXP2(x) __builtin_amdgcn_exp2f(x)
#else
#define EXP2(x) exp2f(x)
#endif

typedef unsigned int __attribute__((address_space(1))) as1_uint;
typedef unsigned int __attribute__((address_space(3))) as3_uint;
__device__ __forceinline__ void gload16(const void* g, void* l) {
    __builtin_amdgcn_global_load_lds((const as1_uint*)g, (as3_uint*)l, 16, 0, 0);
}

// ---------------- fused prep: 7 weight transposes + rmsnorm1 ----------------
__global__ __launch_bounds__(256) void prep_k(
    const float* __restrict__ wq, const float* __restrict__ wk,
    const float* __restrict__ wv, const float* __restrict__ wo,
    const float* __restrict__ wg, const float* __restrict__ wu,
    const float* __restrict__ wd,
    __bf16* __restrict__ qkvT, __bf16* __restrict__ woT,
    __bf16* __restrict__ wguT, __bf16* __restrict__ wdT,
    const float* __restrict__ x, const float* __restrict__ norm1,
    __bf16* __restrict__ hb) {
    __shared__ float t[32][33];
    int bid = blockIdx.x;
    if (bid < 3584) {
        int which = bid >> 9, bx = bid & 511;
        const float* in; __bf16* out; int K, N, mode = 0, phase = 0;
        switch (which) {
            case 0: in = wq; out = qkvT;              K = 512;  N = 1024; break;
            case 1: in = wk; out = qkvT + 1024 * 512; K = 512;  N = 1024; break;
            case 2: in = wv; out = qkvT + 2048 * 512; K = 512;  N = 1024; break;
            case 3: in = wo; out = woT;               K = 1024; N = 512;  break;
            case 4: in = wg; out = wguT;              K = 512;  N = 1024; mode = 1; phase = 0; break;
            case 5: in = wu; out = wguT;              K = 512;  N = 1024; mode = 1; phase = 1; break;
            default: in = wd; out = wdT;              K = 1024; N = 512;  break;
        }
        int ntn = N >> 5;
        int n0 = (bx & (ntn - 1)) * 32;
        int k0 = (bx / ntn) * 32;
        int tx = threadIdx.x & 31, ty = threadIdx.x >> 5;
#pragma unroll
        for (int j = 0; j < 4; ++j)
            t[ty * 4 + j][tx] = in[(size_t)(k0 + ty * 4 + j) * N + n0 + tx];
        __syncthreads();
#pragma unroll
        for (int j = 0; j < 4; ++j) {
            int n = n0 + ty * 4 + j;
            int row = mode ? (((n >> 4) << 5) + phase * 16 + (n & 15)) : n;
            out[(size_t)row * K + k0 + tx] = (__bf16)t[tx][ty * 4 + j];
        }
    } else {
        int row = bid - 3584;
        int tt = threadIdx.x;
        const float* xr = x + (size_t)row * HIDD;
        float2 v = *(const float2*)&xr[tt * 2];
        float ss = v.x * v.x + v.y * v.y;
#pragma unroll
        for (int off = 32; off >= 1; off >>= 1) ss += __shfl_xor(ss, off);
        if ((tt & 63) == 0) t[0][tt >> 6] = ss;
        __syncthreads();
        float tot = t[0][0] + t[0][1] + t[0][2] + t[0][3];
        float r = rsqrtf(tot * (1.0f / HIDD) + 1e-8f);
        hb[(size_t)row * HIDD + tt * 2]     = (__bf16)(v.x * r * norm1[tt * 2]);
        hb[(size_t)row * HIDD + tt * 2 + 1] = (__bf16)(v.y * r * norm1[tt * 2 + 1]);
    }
}

// ---------------- RMSNorm over bf16 input (norm2) ----------------
__global__ __launch_bounds__(256) void rmsnorm_bk(const __bf16* __restrict__ x,
                                                  const float* __restrict__ w,
                                                  __bf16* __restrict__ out) {
    int row = blockIdx.x;
    int t = threadIdx.x;
    const __bf16* xr = x + (size_t)row * HIDD;
    float v0 = (float)xr[t * 2], v1 = (float)xr[t * 2 + 1];
    float ss = v0 * v0 + v1 * v1;
#pragma unroll
    for (int off = 32; off >= 1; off >>= 1) ss += __shfl_xor(ss, off);
    __shared__ float red[4];
    if ((t & 63) == 0) red[t >> 6] = ss;
    __syncthreads();
    float tot = red[0] + red[1] + red[2] + red[3];
    float r = rsqrtf(tot * (1.0f / HIDD) + 1e-8f);
    out[(size_t)row * HIDD + t * 2]     = (__bf16)(v0 * r * w[t * 2]);
    out[(size_t)row * HIDD + t * 2 + 1] = (__bf16)(v1 * r * w[t * 2 + 1]);
}

// ---------------- GEMM: C[M][N] = A[M][K] * Bt[N][K]^T ----------------
// A-DIRECT: A fragments load straight from global (L2-resident activations,
// clean 16-row x 64B coalescing) - A never transits LDS. Only B is staged
// (gload_lds + T2 swizzle). LDS bytes/K-tile halved: the r17 arithmetic shows
// this GEMM structure saturates the 128B/cyc LDS pipe (m97: 127B/cyc at 912TF),
// so time ~ LDS bytes. A-load latency hides under B-staging + barrier drain.
template <int EPI, int TM, int TN, int BK>
__global__ __launch_bounds__(256) void gemm_bt(const __bf16* __restrict__ A,
                                               const __bf16* __restrict__ Bt,
                                               int M, int N, int K,
                                               __bf16* __restrict__ Cb,
                                               float* __restrict__ Cf,
                                               const float* __restrict__ resid,
                                               const float* __restrict__ scale,
                                               const float* __restrict__ cosv,
                                               const float* __restrict__ sinv,
                                               __bf16* __restrict__ kbp,
                                               __bf16* __restrict__ vbp) {
    __shared__ alignas(16) __bf16 Bs[TN][BK];
    constexpr int MI = TM / 32, NI = TN / 32, KKN = BK / 32;
    constexpr int CPB = BK / 8;
    int nwg = gridDim.x * gridDim.y;
    int bid = blockIdx.y * gridDim.x + blockIdx.x;
    int swz = (bid & 7) * (nwg >> 3) + (bid >> 3);
    int bx = swz % gridDim.x, by = swz / gridDim.x;
    int m0 = by * TM, n0 = bx * TN;
    int tid = threadIdx.x;
    int lane = tid & 63, w = tid >> 6;
    int wm = (w >> 1) * (TM / 2), wn = (w & 1) * (TN / 2);
    int lr = lane & 15, lkg = lane >> 4;
    f32x4 acc[MI][NI] = {};
    int nkt = K / BK;
    for (int kt = 0; kt < nkt; ++kt) {
        __syncthreads();
        // A fragments direct from global (no swizzle needed)
        bf16x8 af[KKN][MI];
#pragma unroll
        for (int kk = 0; kk < KKN; ++kk)
#pragma unroll
            for (int mi = 0; mi < MI; ++mi)
                af[kk][mi] = *(const bf16x8*)&A[(size_t)(m0 + wm + mi * 16 + lr) * K
                                                + kt * BK + (kk * 4 + lkg) * 8];
        // B staging to LDS (source-swizzled)
#pragma unroll
        for (int i = 0; i < (TN * BK) / 2048; ++i) {
            int c = i * 256 + tid;
            int row = c / CPB, ch = c % CPB;
            gload16(&Bt[(size_t)(n0 + row) * K + kt * BK + ((ch ^ (row & 7)) << 3)],
                    (__bf16*)Bs + c * 8);
        }
        __syncthreads();
#pragma unroll
        for (int kk = 0; kk < KKN; ++kk) {
            bf16x8 bfv[NI];
#pragma unroll
            for (int ni = 0; ni < NI; ++ni) {
                int row = wn + ni * 16 + lr;
                bfv[ni] = *(const bf16x8*)&Bs[row][(((kk * 4 + lkg) ^ (row & 7)) << 3)];
            }
#pragma unroll
            for (int mi = 0; mi < MI; ++mi)
#pragma unroll
                for (int ni = 0; ni < NI; ++ni)
                    acc[mi][ni] = __builtin_amdgcn_mfma_f32_16x16x32_bf16(
                        af[kk][mi], bfv[ni], acc[mi][ni], 0, 0, 0);
        }
    }
    if (EPI == 1) {
        int col0 = n0 + wn;
        int hh = (col0 >> 6) & 15;
#pragma unroll
        for (int mi = 0; mi < MI; ++mi)
#pragma unroll
            for (int r = 0; r < 4; ++r) {
                int row = m0 + wm + mi * 16 + lkg * 4 + r;
                int s = row & (SEQ - 1);
                size_t hdr = ((size_t)((row >> 11) * 16 + hh) * SEQ + s) * 64;
                if (col0 < 1024) {
#pragma unroll
                    for (int ni = 0; ni < 2; ++ni) {
                        float v1 = acc[mi][ni][r], v2 = acc[mi][ni + 2][r];
                        int d = ni * 16 + lr;
                        float c = cosv[s * 32 + d], sn = sinv[s * 32 + d];
                        size_t i1 = (size_t)row * 1024 + col0 + d;
                        Cb[i1]      = (__bf16)((v1 * c - v2 * sn) * QSCALE);
                        Cb[i1 + 32] = (__bf16)((v2 * c + v1 * sn) * QSCALE);
                    }
                } else if (col0 < 2048) {
#pragma unroll
                    for (int ni = 0; ni < 2; ++ni) {
                        float v1 = acc[mi][ni][r], v2 = acc[mi][ni + 2][r];
                        int d = ni * 16 + lr;
                        float c = cosv[s * 32 + d], sn = sinv[s * 32 + d];
                        kbp[hdr + d]      = (__bf16)(v1 * c - v2 * sn);
                        kbp[hdr + d + 32] = (__bf16)(v2 * c + v1 * sn);
                    }
                } else {
#pragma unroll
                    for (int ni = 0; ni < 4; ++ni)
                        vbp[hdr + ni * 16 + lr] = (__bf16)acc[mi][ni][r];
                }
            }
    } else if (EPI == 3) {
#pragma unroll
        for (int mi = 0; mi < MI; ++mi)
#pragma unroll
            for (int r = 0; r < 4; ++r) {
                int row = m0 + wm + mi * 16 + lkg * 4 + r;
#pragma unroll
                for (int ni = 0; ni < 4; ni += 2) {
                    float g = acc[mi][ni][r], u = acc[mi][ni + 1][r];
                    float mv = (g / (1.0f + __expf(-g))) * u;
                    int j = (((n0 + wn + ni * 16) >> 5) << 4) + lr;
                    Cb[(size_t)row * 1024 + j] = (__bf16)mv;
                }
            }
    } else if (EPI == 4) {
#pragma unroll
        for (int mi = 0; mi < MI; ++mi)
#pragma unroll
            for (int ni = 0; ni < NI; ++ni)
#pragma unroll
                for (int r = 0; r < 4; ++r) {
                    int row = m0 + wm + mi * 16 + lkg * 4 + r;
                    int col = n0 + wn + ni * 16 + lr;
                    size_t idx = (size_t)row * N + col;
                    Cb[idx] = (__bf16)(resid[idx] + acc[mi][ni][r] * scale[col]);
                }
    } else if (EPI == 5) {
        const __bf16* rb = (const __bf16*)Cb;
#pragma unroll
        for (int mi = 0; mi < MI; ++mi)
#pragma unroll
            for (int ni = 0; ni < NI; ++ni)
#pragma unroll
                for (int r = 0; r < 4; ++r) {
                    int row = m0 + wm + mi * 16 + lkg * 4 + r;
                    int col = n0 + wn + ni * 16 + lr;
                    size_t idx = (size_t)row * N + col;
                    Cf[idx] = (float)rb[idx] + acc[mi][ni][r] * scale[col];
                }
    }
}

// ---------------- V transpose+permute ----------------
__global__ __launch_bounds__(256) void kvprep_k(const __bf16* __restrict__ vb,
                                                __bf16* __restrict__ vtb) {
    __shared__ __bf16 tr[64 * 132];
    int bh = blockIdx.x, st = blockIdx.y;
    int tid = threadIdx.x;
    size_t base = ((size_t)bh * SEQ + st * 128) * 64;
#pragma unroll
    for (int i = 0; i < 4; ++i) {
        int c = i * 256 + tid;
        int vr = c >> 3, ch = c & 7;
        uint4 v = *(const uint4*)&vb[base + (size_t)vr * 64 + ch * 8];
        const __bf16* ve = (const __bf16*)&v;
#pragma unroll
        for (int j = 0; j < 8; ++j) tr[(ch * 8 + j) * 132 + vr] = ve[j];
    }
    __syncthreads();
#pragma unroll
    for (int i = 0; i < 4; ++i) {
        int c = i * 256 + tid;
        int dv = c >> 4, rest = c & 15;
        int t64 = rest >> 3, cc = rest & 7;
        int K0 = t64 * 64 + 32 * (cc >> 2) + 4 * (cc & 3);
        __bf16 outv[8];
#pragma unroll
        for (int j = 0; j < 4; ++j) outv[j] = tr[dv * 132 + K0 + j];
#pragma unroll
        for (int j = 0; j < 4; ++j) outv[4 + j] = tr[dv * 132 + K0 + 16 + j];
        *(uint4*)&vtb[((size_t)bh * 64 + dv) * SEQ + st * 128 + t64 * 64 + cc * 8] =
            *(uint4*)outv;
    }
}

// ---------------- causal flash attention: dual wave-group, coalesced staging ----------------
__global__ __launch_bounds__(512, 4) void attn_k(const __bf16* __restrict__ qb,
                                                 const __bf16* __restrict__ kb,
                                                 const __bf16* __restrict__ vtb,
                                                 __bf16* __restrict__ outp) {
    __shared__ alignas(16) __bf16 KS[2][2][4096];
    __shared__ alignas(16) __bf16 VS[2][2][4096];
    int bh = blockIdx.x;
    int b = bh >> 4, h = bh & 15;
    int y = blockIdx.y;
    int qbA = y, qbB = 31 - y;
    int TA = y + 1;
    int tid = threadIdx.x;
    int grp = tid >> 8;
    int tg  = tid & 255;
    int lane = tid & 63, wg = tg >> 6;
    int lq = lane & 15, g = lane >> 4;
    size_t tokb = (size_t)b * SEQ;
    int qr0A = qbA * 64 + wg * 16, qr0B = qbB * 64 + wg * 16;

    bf16x8 ones8;
#pragma unroll
    for (int e = 0; e < 8; ++e) ones8[e] = (__bf16)1.0f;

    f32x4 oa[4] = {};
    f32x4 ol = {};

#define STAGE_K(kbn, kdst)                                                                         \
    {                                                                                              \
        _Pragma("unroll")                                                                          \
        for (int i = 0; i < 2; ++i) {                                                              \
            int c = i * 256 + tg;                                                                  \
            int kr = c >> 3, ch = c & 7;                                                           \
            gload16(&kb[((size_t)bh * SEQ + (kbn) * 64 + kr) * 64 + ((ch ^ (kr & 7)) << 3)],       \
                    (kdst) + c * 8);                                                               \
        }                                                                                          \
    }

#define STAGE_V(kbn, vdst)                                                                         \
    {                                                                                              \
        _Pragma("unroll")                                                                          \
        for (int i = 0; i < 2; ++i) {                                                              \
            int c = i * 256 + tg;                                                                  \
            int vr = c >> 3, ch = c & 7;                                                           \
            gload16(&vtb[((size_t)bh * 64 + vr) * SEQ + (kbn) * 64 + ((ch ^ (vr & 7)) << 3)],      \
                    (vdst) + c * 8);                                                               \
        }                                                                                          \
    }

#define QK_S(sc, aq, ksrc)                                                                         \
    {                                                                                              \
        __builtin_amdgcn_s_setprio(1);                                                             \
        _Pragma("unroll")                                                                          \
        for (int jt = 0; jt < 4; ++jt)                                                             \
            _Pragma("unroll")                                                                      \
            for (int ks = 0; ks < 2; ++ks) {                                                       \
                bf16x8 bk = *(const bf16x8*)&(ksrc)[(jt * 16 + lq) * 64 + (((ks * 4 + g) ^ (lq & 7)) << 3)]; \
                sc[jt] = __builtin_amdgcn_mfma_f32_16x16x32_bf16(bk, aq[ks], sc[jt], 0, 0, 0);     \
            }                                                                                      \
        __builtin_amdgcn_s_setprio(0);                                                             \
    }

#define MASK_S(sc, qr0_t, kb64)                                                                    \
    {                                                                                              \
        int qabs = (qr0_t) + lq;                                                                   \
        _Pragma("unroll")                                                                          \
        for (int jt = 0; jt < 4; ++jt)                                                             \
            _Pragma("unroll")                                                                      \
            for (int r = 0; r < 4; ++r) {                                                          \
                int key = (kb64) * 64 + jt * 16 + g * 4 + r;                                       \
                if (key > qabs) sc[jt][r] = -1e9f;                                                 \
            }                                                                                      \
    }

#define EXP_S(sc)                                                                                  \
    _Pragma("unroll")                                                                              \
    for (int jt = 0; jt < 4; ++jt)                                                                 \
        _Pragma("unroll")                                                                          \
        for (int r = 0; r < 4; ++r) sc[jt][r] = EXP2(sc[jt][r]);

#define PV_S(sc, vsrc)                                                                             \
    {                                                                                              \
        __builtin_amdgcn_s_setprio(1);                                                             \
        _Pragma("unroll")                                                                          \
        for (int ks2 = 0; ks2 < 2; ++ks2) {                                                        \
            bf16x8 pfv;                                                                            \
            _Pragma("unroll")                                                                      \
            for (int e = 0; e < 4; ++e) {                                                          \
                pfv[e]     = (__bf16)sc[2 * ks2][e];                                               \
                pfv[e + 4] = (__bf16)sc[2 * ks2 + 1][e];                                           \
            }                                                                                      \
            ol = __builtin_amdgcn_mfma_f32_16x16x32_bf16(ones8, pfv, ol, 0, 0, 0);                 \
            _Pragma("unroll")                                                                      \
            for (int dt = 0; dt < 4; ++dt) {                                                       \
                bf16x8 av = *(const bf16x8*)&(vsrc)[(dt * 16 + lq) * 64 + (((ks2 * 4 + g) ^ (lq & 7)) << 3)]; \
                oa[dt] = __builtin_amdgcn_mfma_f32_16x16x32_bf16(av, pfv, oa[dt], 0, 0, 0);        \
            }                                                                                      \
        }                                                                                          \
        __builtin_amdgcn_s_setprio(0);                                                             \
    }

    if (grp == 0) {
        bf16x8 aqB[2];
#pragma unroll
        for (int ks = 0; ks < 2; ++ks)
            aqB[ks] = *(const bf16x8*)&qb[(tokb + qr0B + lq) * 1024 + h * 64 + ks * 32 + g * 8];
        STAGE_K(0, KS[0][0]);
        STAGE_V(0, VS[0][0]);
        __syncthreads();
        for (int it = 0; it < 17; ++it) {
            int buf = it & 1;
            bool pf = it < 16;
            if (pf) {
                STAGE_K(it + 1, KS[0][buf ^ 1]);
                STAGE_V(it + 1, VS[0][buf ^ 1]);
            }
            f32x4 sc[4] = {};
            QK_S(sc, aqB, KS[0][buf]);
            if (it == qbB) MASK_S(sc, qr0B, it);
            EXP_S(sc);
            PV_S(sc, VS[0][buf]);
            __syncthreads();
        }
    } else {
        {
            bf16x8 aqA[2];
#pragma unroll
            for (int ks = 0; ks < 2; ++ks)
                aqA[ks] = *(const bf16x8*)&qb[(tokb + qr0A + lq) * 1024 + h * 64 + ks * 32 + g * 8];
            __syncthreads();
            for (int it = 0; it < TA; ++it) {
                int buf = it & 1;
                if (it == TA - 1) {
                    STAGE_K(17, KS[1][0]);
                    STAGE_V(17, VS[1][0]);
                }
                f32x4 sc[4] = {};
                QK_S(sc, aqA, KS[0][buf]);
                if (it == qbA) MASK_S(sc, qr0A, it);
                EXP_S(sc);
                PV_S(sc, VS[0][buf]);
                __syncthreads();
            }
        }
        {
            float inv = 1.0f / ol[0];
#pragma unroll
            for (int dt = 0; dt < 4; ++dt) {
                bf16x4 ov;
#pragma unroll
                for (int r = 0; r < 4; ++r) ov[r] = (__bf16)(oa[dt][r] * inv);
                *(bf16x4*)&outp[(tokb + qr0A + lq) * 1024 + h * 64 + dt * 16 + g * 4] = ov;
                oa[dt] = (f32x4){0.f, 0.f, 0.f, 0.f};
            }
            ol = (f32x4){0.f, 0.f, 0.f, 0.f};
        }
        {
            bf16x8 aqB[2];
#pragma unroll
            for (int ks = 0; ks < 2; ++ks)
                aqB[ks] = *(const bf16x8*)&qb[(tokb + qr0B + lq) * 1024 + h * 64 + ks * 32 + g * 8];
            int cnt = 16 - TA;
            for (int j = 0; j < cnt; ++j) {
                int buf = j & 1;
                if (j + 1 < cnt) {
                    STAGE_K(17 + j + 1, KS[1][buf ^ 1]);
                    STAGE_V(17 + j + 1, VS[1][buf ^ 1]);
                }
                f32x4 sc[4] = {};
                int kb64 = 17 + j;
                QK_S(sc, aqB, KS[1][buf]);
                if (kb64 == qbB) MASK_S(sc, qr0B, kb64);
                EXP_S(sc);
                PV_S(sc, VS[1][buf]);
                __syncthreads();
            }
        }
        __syncthreads();
    }

    float* mrg_oa = (float*)KS[1];
    float* mrg_ol = (float*)VS[1];
    if (grp == 1) {
#pragma unroll
        for (int dt = 0; dt < 4; ++dt)
#pragma unroll
            for (int r = 0; r < 4; ++r) mrg_oa[tg * 16 + dt * 4 + r] = oa[dt][r];
        mrg_ol[tg] = ol[0];
    }
    __syncthreads();
    if (grp == 0) {
        float l = ol[0] + mrg_ol[tg];
        float inv = 1.0f / l;
#pragma unroll
        for (int dt = 0; dt < 4; ++dt) {
            bf16x4 ov;
#pragma unroll
            for (int r = 0; r < 4; ++r)
                ov[r] = (__bf16)((oa[dt][r] + mrg_oa[tg * 16 + dt * 4 + r]) * inv);
            *(bf16x4*)&outp[(tokb + qr0B + lq) * 1024 + h * 64 + dt * 16 + g * 4] = ov;
        }
    }
#undef STAGE_K
#undef STAGE_V
#undef QK_S
#undef MASK_S
#undef EXP_S
#undef PV_S
}

// ---------------- launch ----------------
extern "C" void kernel_launch(void* const* d_in, const int* in_sizes, int n_in,
                              void* d_out, int out_size, void* d_ws, size_t ws_size,
                              hipStream_t stream) {
    const float* x       = (const float*)d_in[0];
    const float* cosv    = (const float*)d_in[1];
    const float* sinv    = (const float*)d_in[2];
    const float* wq      = (const float*)d_in[4];
    const float* wk      = (const float*)d_in[5];
    const float* wv      = (const float*)d_in[6];
    const float* wo      = (const float*)d_in[7];
    const float* wgate   = (const float*)d_in[8];
    const float* wup     = (const float*)d_in[9];
    const float* wdown   = (const float*)d_in[10];
    const float* norm1   = (const float*)d_in[11];
    const float* norm2   = (const float*)d_in[12];
    const float* ls_attn = (const float*)d_in[13];
    const float* ls_mlp  = (const float*)d_in[14];

    char* ws = (char*)d_ws;
    __bf16* wqkvT = (__bf16*)(ws + OFF_WQKVT);
    __bf16* woT   = (__bf16*)(ws + OFF_WOT);
    __bf16* wguT  = (__bf16*)(ws + OFF_WGUT);
    __bf16* wdT   = (__bf16*)(ws + OFF_WDT);
    __bf16* hb    = (__bf16*)(ws + OFF_HB);
    __bf16* qbuf  = (__bf16*)(ws + OFF_QB);
    __bf16* kbuf  = (__bf16*)(ws + OFF_KB);
    __bf16* vbuf  = (__bf16*)(ws + OFF_VB);
    __bf16* vtbuf = (__bf16*)(ws + OFF_H2);
    __bf16* attnb = (__bf16*)(ws + OFF_ATTN);
    __bf16* h2b   = (__bf16*)(ws + OFF_H2);
    __bf16* gb    = (__bf16*)(ws + OFF_G);
    __bf16* mb    = (__bf16*)(ws + OFF_M);
    float*  outf  = (float*)d_out;

    prep_k<<<7680, 256, 0, stream>>>(
        wq, wk, wv, wo, wgate, wup, wdown, wqkvT, woT, wguT, wdT, x, norm1, hb);
    gemm_bt<1, 128, 128, 64><<<dim3(QKVN / 128, NTOK / 128), 256, 0, stream>>>(
        hb, wqkvT, NTOK, QKVN, 512, qbuf, nullptr, nullptr, nullptr, cosv, sinv, kbuf, vbuf);
    kvprep_k<<<dim3(NB * NHEAD, SEQ / 128), 256, 0, stream>>>(vbuf, vtbuf);
    attn_k<<<dim3(NB * NHEAD, 16), 512, 0, stream>>>(qbuf, kbuf, vtbuf, attnb);
    gemm_bt<4, 64, 64, 128><<<dim3(HIDD / 64, NTOK / 64), 256, 0, stream>>>(
        attnb, woT, NTOK, HIDD, 1024, h2b, nullptr, x, ls_attn, nullptr, nullptr, nullptr, nullptr);
    rmsnorm_bk<<<NTOK, 256, 0, stream>>>(h2b, norm2, gb);
    gemm_bt<3, 128, 128, 64><<<dim3(GUN / 128, NTOK / 128), 256, 0, stream>>>(
        gb, wguT, NTOK, GUN, 512, mb, nullptr, nullptr, nullptr, nullptr, nullptr, nullptr, nullptr);
    gemm_bt<5, 64, 64, 128><<<dim3(HIDD / 64, NTOK / 64), 256, 0, stream>>>(
        mb, wdT, NTOK, HIDD, 1024, h2b, outf, nullptr, ls_mlp, nullptr, nullptr, nullptr, nullptr);
}

// Round 19
// 104.858 us; speedup vs baseline: 1.4299x; 1.4299x over previous
//
#include <hip/hip_runtime.h>
#include <hip/hip_bf16.h>

typedef __bf16 bf16x8 __attribute__((ext_vector_type(8)));
typedef __bf16 bf16x4 __attribute__((ext_vector_type(4)));
typedef float f32x4 __attribute__((ext_vector_type(4)));

#define SEQ   2048
#define NB    2
#define NTOK  4096
#define HIDD  512
#define NHEAD 16
#define DHEAD 64
#define QKVN  3072
#define GUN   2048

// workspace layout (bytes)
#define OFF_WQKVT  0u
#define OFF_WOT    3145728u
#define OFF_WGUT   4194304u
#define OFF_WDT    6291456u
#define OFF_HB     7340032u
#define OFF_QB     11534336u                  // qb [4096][1024] bf16
#define OFF_KB     (OFF_QB + 8388608u)        // kb [32][2048][64] bf16
#define OFF_M      (OFF_QB + 16777216u)       // mb (gate*up output)
#define OFF_ATTN   36700160u
#define OFF_H2     45088768u                  // vtb during attn; h2b bf16 after
#define OFF_G      53477376u

#define QSCALE 0.1803368801111731f            // 0.125 * log2(e)

#if __has_builtin(__builtin_amdgcn_exp2f)
#define EXP2(x) __builtin_amdgcn_exp2f(x)
#else
#define EXP2(x) exp2f(x)
#endif

typedef unsigned int __attribute__((address_space(1))) as1_uint;
typedef unsigned int __attribute__((address_space(3))) as3_uint;
__device__ __forceinline__ void gload16(const void* g, void* l) {
    __builtin_amdgcn_global_load_lds((const as1_uint*)g, (as3_uint*)l, 16, 0, 0);
}

// ---------------- fused prep: 7 weight transposes + rmsnorm1 ----------------
__global__ __launch_bounds__(256) void prep_k(
    const float* __restrict__ wq, const float* __restrict__ wk,
    const float* __restrict__ wv, const float* __restrict__ wo,
    const float* __restrict__ wg, const float* __restrict__ wu,
    const float* __restrict__ wd,
    __bf16* __restrict__ qkvT, __bf16* __restrict__ woT,
    __bf16* __restrict__ wguT, __bf16* __restrict__ wdT,
    const float* __restrict__ x, const float* __restrict__ norm1,
    __bf16* __restrict__ hb) {
    __shared__ float t[32][33];
    int bid = blockIdx.x;
    if (bid < 3584) {
        int which = bid >> 9, bx = bid & 511;
        const float* in; __bf16* out; int K, N, mode = 0, phase = 0;
        switch (which) {
            case 0: in = wq; out = qkvT;              K = 512;  N = 1024; break;
            case 1: in = wk; out = qkvT + 1024 * 512; K = 512;  N = 1024; break;
            case 2: in = wv; out = qkvT + 2048 * 512; K = 512;  N = 1024; break;
            case 3: in = wo; out = woT;               K = 1024; N = 512;  break;
            case 4: in = wg; out = wguT;              K = 512;  N = 1024; mode = 1; phase = 0; break;
            case 5: in = wu; out = wguT;              K = 512;  N = 1024; mode = 1; phase = 1; break;
            default: in = wd; out = wdT;              K = 1024; N = 512;  break;
        }
        int ntn = N >> 5;
        int n0 = (bx & (ntn - 1)) * 32;
        int k0 = (bx / ntn) * 32;
        int tx = threadIdx.x & 31, ty = threadIdx.x >> 5;
#pragma unroll
        for (int j = 0; j < 4; ++j)
            t[ty * 4 + j][tx] = in[(size_t)(k0 + ty * 4 + j) * N + n0 + tx];
        __syncthreads();
#pragma unroll
        for (int j = 0; j < 4; ++j) {
            int n = n0 + ty * 4 + j;
            int row = mode ? (((n >> 4) << 5) + phase * 16 + (n & 15)) : n;
            out[(size_t)row * K + k0 + tx] = (__bf16)t[tx][ty * 4 + j];
        }
    } else {
        int row = bid - 3584;
        int tt = threadIdx.x;
        const float* xr = x + (size_t)row * HIDD;
        float2 v = *(const float2*)&xr[tt * 2];
        float ss = v.x * v.x + v.y * v.y;
#pragma unroll
        for (int off = 32; off >= 1; off >>= 1) ss += __shfl_xor(ss, off);
        if ((tt & 63) == 0) t[0][tt >> 6] = ss;
        __syncthreads();
        float tot = t[0][0] + t[0][1] + t[0][2] + t[0][3];
        float r = rsqrtf(tot * (1.0f / HIDD) + 1e-8f);
        hb[(size_t)row * HIDD + tt * 2]     = (__bf16)(v.x * r * norm1[tt * 2]);
        hb[(size_t)row * HIDD + tt * 2 + 1] = (__bf16)(v.y * r * norm1[tt * 2 + 1]);
    }
}

// ---------------- RMSNorm over bf16 input (norm2) ----------------
__global__ __launch_bounds__(256) void rmsnorm_bk(const __bf16* __restrict__ x,
                                                  const float* __restrict__ w,
                                                  __bf16* __restrict__ out) {
    int row = blockIdx.x;
    int t = threadIdx.x;
    const __bf16* xr = x + (size_t)row * HIDD;
    float v0 = (float)xr[t * 2], v1 = (float)xr[t * 2 + 1];
    float ss = v0 * v0 + v1 * v1;
#pragma unroll
    for (int off = 32; off >= 1; off >>= 1) ss += __shfl_xor(ss, off);
    __shared__ float red[4];
    if ((t & 63) == 0) red[t >> 6] = ss;
    __syncthreads();
    float tot = red[0] + red[1] + red[2] + red[3];
    float r = rsqrtf(tot * (1.0f / HIDD) + 1e-8f);
    out[(size_t)row * HIDD + t * 2]     = (__bf16)(v0 * r * w[t * 2]);
    out[(size_t)row * HIDD + t * 2 + 1] = (__bf16)(v1 * r * w[t * 2 + 1]);
}

// ---------------- GEMM: C[M][N] = A[M][K] * Bt[N][K]^T ----------------
// r17 structure (A+B both LDS-staged via gload_lds, T2 swizzle, XCD swizzle).
// r18's A-direct refuted: fragment-granularity global loads on the critical
// path lose to bulk staging (MfmaUtil 8.8%, FETCH 2x). EPI1 V-cols fuse the
// kvprep transpose+permute into the epilogue, reusing staging LDS.
template <int EPI, int TM, int TN, int BK>
__global__ __launch_bounds__(256) void gemm_bt(const __bf16* __restrict__ A,
                                               const __bf16* __restrict__ Bt,
                                               int M, int N, int K,
                                               __bf16* __restrict__ Cb,
                                               float* __restrict__ Cf,
                                               const float* __restrict__ resid,
                                               const float* __restrict__ scale,
                                               const float* __restrict__ cosv,
                                               const float* __restrict__ sinv,
                                               __bf16* __restrict__ kbp,
                                               __bf16* __restrict__ vtbp) {
    __shared__ alignas(16) __bf16 smem[TM * BK + TN * BK];
    __bf16 (*As)[BK] = (__bf16(*)[BK])smem;
    __bf16 (*Bs)[BK] = (__bf16(*)[BK])(smem + TM * BK);
    constexpr int MI = TM / 32, NI = TN / 32;
    constexpr int CPB = BK / 8;
    int nwg = gridDim.x * gridDim.y;
    int bid = blockIdx.y * gridDim.x + blockIdx.x;
    int swz = (bid & 7) * (nwg >> 3) + (bid >> 3);
    int bx = swz % gridDim.x, by = swz / gridDim.x;
    int m0 = by * TM, n0 = bx * TN;
    int tid = threadIdx.x;
    int lane = tid & 63, w = tid >> 6;
    int wm = (w >> 1) * (TM / 2), wn = (w & 1) * (TN / 2);
    int lr = lane & 15, lkg = lane >> 4;
    f32x4 acc[MI][NI] = {};
    int nkt = K / BK;
    for (int kt = 0; kt < nkt; ++kt) {
        __syncthreads();
#pragma unroll
        for (int i = 0; i < (TM * BK) / 2048; ++i) {
            int c = i * 256 + tid;
            int row = c / CPB, ch = c % CPB;
            gload16(&A[(size_t)(m0 + row) * K + kt * BK + ((ch ^ (row & 7)) << 3)],
                    (__bf16*)As + c * 8);
        }
#pragma unroll
        for (int i = 0; i < (TN * BK) / 2048; ++i) {
            int c = i * 256 + tid;
            int row = c / CPB, ch = c % CPB;
            gload16(&Bt[(size_t)(n0 + row) * K + kt * BK + ((ch ^ (row & 7)) << 3)],
                    (__bf16*)Bs + c * 8);
        }
        __syncthreads();
#pragma unroll
        for (int kk = 0; kk < BK / 32; ++kk) {
            bf16x8 af[MI], bfv[NI];
#pragma unroll
            for (int mi = 0; mi < MI; ++mi) {
                int row = wm + mi * 16 + lr;
                af[mi] = *(const bf16x8*)&As[row][(((kk * 4 + lkg) ^ (row & 7)) << 3)];
            }
#pragma unroll
            for (int ni = 0; ni < NI; ++ni) {
                int row = wn + ni * 16 + lr;
                bfv[ni] = *(const bf16x8*)&Bs[row][(((kk * 4 + lkg) ^ (row & 7)) << 3)];
            }
#pragma unroll
            for (int mi = 0; mi < MI; ++mi)
#pragma unroll
                for (int ni = 0; ni < NI; ++ni)
                    acc[mi][ni] = __builtin_amdgcn_mfma_f32_16x16x32_bf16(
                        af[mi], bfv[ni], acc[mi][ni], 0, 0, 0);
        }
    }
    if (EPI == 1) {
        int col0 = n0 + wn;                 // block entirely within Q/K/V region
        int hh = (col0 >> 6) & 15;
        if (col0 < 1024) {                  // Q: rope * QSCALE -> qb
#pragma unroll
            for (int mi = 0; mi < MI; ++mi)
#pragma unroll
                for (int r = 0; r < 4; ++r) {
                    int row = m0 + wm + mi * 16 + lkg * 4 + r;
                    int s = row & (SEQ - 1);
#pragma unroll
                    for (int ni = 0; ni < 2; ++ni) {
                        float v1 = acc[mi][ni][r], v2 = acc[mi][ni + 2][r];
                        int d = ni * 16 + lr;
                        float c = cosv[s * 32 + d], sn = sinv[s * 32 + d];
                        size_t i1 = (size_t)row * 1024 + col0 + d;
                        Cb[i1]      = (__bf16)((v1 * c - v2 * sn) * QSCALE);
                        Cb[i1 + 32] = (__bf16)((v2 * c + v1 * sn) * QSCALE);
                    }
                }
        } else if (col0 < 2048) {           // K: rope -> kb compact
#pragma unroll
            for (int mi = 0; mi < MI; ++mi)
#pragma unroll
                for (int r = 0; r < 4; ++r) {
                    int row = m0 + wm + mi * 16 + lkg * 4 + r;
                    int s = row & (SEQ - 1);
                    size_t hdr = ((size_t)((row >> 11) * 16 + hh) * SEQ + s) * 64;
#pragma unroll
                    for (int ni = 0; ni < 2; ++ni) {
                        float v1 = acc[mi][ni][r], v2 = acc[mi][ni + 2][r];
                        int d = ni * 16 + lr;
                        float c = cosv[s * 32 + d], sn = sinv[s * 32 + d];
                        kbp[hdr + d]      = (__bf16)(v1 * c - v2 * sn);
                        kbp[hdr + d + 32] = (__bf16)(v2 * c + v1 * sn);
                    }
                }
        } else {                            // V: fused transpose+permute -> vtb
            __bf16* tr = smem;              // 128 cols x 66-stride (16.9KB), LDS reused
            int bh0 = (m0 >> 11) * 16 + ((n0 >> 6) & 15);
#pragma unroll
            for (int p = 0; p < 2; ++p) {   // two 64-token passes
                __syncthreads();
                if ((wm >> 6) == p) {
#pragma unroll
                    for (int mi = 0; mi < MI; ++mi)
#pragma unroll
                        for (int ni = 0; ni < NI; ++ni)
#pragma unroll
                            for (int r = 0; r < 4; ++r) {
                                int row_l = mi * 16 + lkg * 4 + r;
                                int col_l = wn + ni * 16 + lr;
                                tr[col_l * 66 + row_l] = (__bf16)acc[mi][ni][r];
                            }
                }
                __syncthreads();
                int s0 = (m0 & (SEQ - 1)) + p * 64;
#pragma unroll
                for (int i = 0; i < 4; ++i) {
                    int c = i * 256 + tid;
                    int col_l = c >> 3, cc = c & 7;
                    int dv = col_l & 63, h3 = col_l >> 6;
                    int K0 = 32 * (cc >> 2) + 4 * (cc & 3);
                    __bf16 outv[8];
#pragma unroll
                    for (int j = 0; j < 4; ++j) outv[j]     = tr[col_l * 66 + K0 + j];
#pragma unroll
                    for (int j = 0; j < 4; ++j) outv[4 + j] = tr[col_l * 66 + K0 + 16 + j];
                    *(uint4*)&vtbp[((size_t)(bh0 + h3) * 64 + dv) * SEQ + s0 + cc * 8] =
                        *(uint4*)outv;
                }
            }
        }
    } else if (EPI == 3) {
#pragma unroll
        for (int mi = 0; mi < MI; ++mi)
#pragma unroll
            for (int r = 0; r < 4; ++r) {
                int row = m0 + wm + mi * 16 + lkg * 4 + r;
#pragma unroll
                for (int ni = 0; ni < 4; ni += 2) {
                    float g = acc[mi][ni][r], u = acc[mi][ni + 1][r];
                    float mv = (g / (1.0f + __expf(-g))) * u;
                    int j = (((n0 + wn + ni * 16) >> 5) << 4) + lr;
                    Cb[(size_t)row * 1024 + j] = (__bf16)mv;
                }
            }
    } else if (EPI == 4) {                  // bf16 out = f32 resid + acc*scale
#pragma unroll
        for (int mi = 0; mi < MI; ++mi)
#pragma unroll
            for (int ni = 0; ni < NI; ++ni)
#pragma unroll
                for (int r = 0; r < 4; ++r) {
                    int row = m0 + wm + mi * 16 + lkg * 4 + r;
                    int col = n0 + wn + ni * 16 + lr;
                    size_t idx = (size_t)row * N + col;
                    Cb[idx] = (__bf16)(resid[idx] + acc[mi][ni][r] * scale[col]);
                }
    } else if (EPI == 5) {                  // f32 out = bf16 resid(Cb) + acc*scale
        const __bf16* rb = (const __bf16*)Cb;
#pragma unroll
        for (int mi = 0; mi < MI; ++mi)
#pragma unroll
            for (int ni = 0; ni < NI; ++ni)
#pragma unroll
                for (int r = 0; r < 4; ++r) {
                    int row = m0 + wm + mi * 16 + lkg * 4 + r;
                    int col = n0 + wn + ni * 16 + lr;
                    size_t idx = (size_t)row * N + col;
                    Cf[idx] = (float)rb[idx] + acc[mi][ni][r] * scale[col];
                }
    }
}

// ---------------- causal flash attention: dual wave-group, coalesced staging ----------------
__global__ __launch_bounds__(512, 4) void attn_k(const __bf16* __restrict__ qb,
                                                 const __bf16* __restrict__ kb,
                                                 const __bf16* __restrict__ vtb,
                                                 __bf16* __restrict__ outp) {
    __shared__ alignas(16) __bf16 KS[2][2][4096];
    __shared__ alignas(16) __bf16 VS[2][2][4096];
    int bh = blockIdx.x;
    int b = bh >> 4, h = bh & 15;
    int y = blockIdx.y;
    int qbA = y, qbB = 31 - y;
    int TA = y + 1;
    int tid = threadIdx.x;
    int grp = tid >> 8;
    int tg  = tid & 255;
    int lane = tid & 63, wg = tg >> 6;
    int lq = lane & 15, g = lane >> 4;
    size_t tokb = (size_t)b * SEQ;
    int qr0A = qbA * 64 + wg * 16, qr0B = qbB * 64 + wg * 16;

    bf16x8 ones8;
#pragma unroll
    for (int e = 0; e < 8; ++e) ones8[e] = (__bf16)1.0f;

    f32x4 oa[4] = {};
    f32x4 ol = {};

#define STAGE_K(kbn, kdst)                                                                         \
    {                                                                                              \
        _Pragma("unroll")                                                                          \
        for (int i = 0; i < 2; ++i) {                                                              \
            int c = i * 256 + tg;                                                                  \
            int kr = c >> 3, ch = c & 7;                                                           \
            gload16(&kb[((size_t)bh * SEQ + (kbn) * 64 + kr) * 64 + ((ch ^ (kr & 7)) << 3)],       \
                    (kdst) + c * 8);                                                               \
        }                                                                                          \
    }

#define STAGE_V(kbn, vdst)                                                                         \
    {                                                                                              \
        _Pragma("unroll")                                                                          \
        for (int i = 0; i < 2; ++i) {                                                              \
            int c = i * 256 + tg;                                                                  \
            int vr = c >> 3, ch = c & 7;                                                           \
            gload16(&vtb[((size_t)bh * 64 + vr) * SEQ + (kbn) * 64 + ((ch ^ (vr & 7)) << 3)],      \
                    (vdst) + c * 8);                                                               \
        }                                                                                          \
    }

#define QK_S(sc, aq, ksrc)                                                                         \
    {                                                                                              \
        __builtin_amdgcn_s_setprio(1);                                                             \
        _Pragma("unroll")                                                                          \
        for (int jt = 0; jt < 4; ++jt)                                                             \
            _Pragma("unroll")                                                                      \
            for (int ks = 0; ks < 2; ++ks) {                                                       \
                bf16x8 bk = *(const bf16x8*)&(ksrc)[(jt * 16 + lq) * 64 + (((ks * 4 + g) ^ (lq & 7)) << 3)]; \
                sc[jt] = __builtin_amdgcn_mfma_f32_16x16x32_bf16(bk, aq[ks], sc[jt], 0, 0, 0);     \
            }                                                                                      \
        __builtin_amdgcn_s_setprio(0);                                                             \
    }

#define MASK_S(sc, qr0_t, kb64)                                                                    \
    {                                                                                              \
        int qabs = (qr0_t) + lq;                                                                   \
        _Pragma("unroll")                                                                          \
        for (int jt = 0; jt < 4; ++jt)                                                             \
            _Pragma("unroll")                                                                      \
            for (int r = 0; r < 4; ++r) {                                                          \
                int key = (kb64) * 64 + jt * 16 + g * 4 + r;                                       \
                if (key > qabs) sc[jt][r] = -1e9f;                                                 \
            }                                                                                      \
    }

#define EXP_S(sc)                                                                                  \
    _Pragma("unroll")                                                                              \
    for (int jt = 0; jt < 4; ++jt)                                                                 \
        _Pragma("unroll")                                                                          \
        for (int r = 0; r < 4; ++r) sc[jt][r] = EXP2(sc[jt][r]);

#define PV_S(sc, vsrc)                                                                             \
    {                                                                                              \
        __builtin_amdgcn_s_setprio(1);                                                             \
        _Pragma("unroll")                                                                          \
        for (int ks2 = 0; ks2 < 2; ++ks2) {                                                        \
            bf16x8 pfv;                                                                            \
            _Pragma("unroll")                                                                      \
            for (int e = 0; e < 4; ++e) {                                                          \
                pfv[e]     = (__bf16)sc[2 * ks2][e];                                               \
                pfv[e + 4] = (__bf16)sc[2 * ks2 + 1][e];                                           \
            }                                                                                      \
            ol = __builtin_amdgcn_mfma_f32_16x16x32_bf16(ones8, pfv, ol, 0, 0, 0);                 \
            _Pragma("unroll")                                                                      \
            for (int dt = 0; dt < 4; ++dt) {                                                       \
                bf16x8 av = *(const bf16x8*)&(vsrc)[(dt * 16 + lq) * 64 + (((ks2 * 4 + g) ^ (lq & 7)) << 3)]; \
                oa[dt] = __builtin_amdgcn_mfma_f32_16x16x32_bf16(av, pfv, oa[dt], 0, 0, 0);        \
            }                                                                                      \
        }                                                                                          \
        __builtin_amdgcn_s_setprio(0);                                                             \
    }

    if (grp == 0) {
        bf16x8 aqB[2];
#pragma unroll
        for (int ks = 0; ks < 2; ++ks)
            aqB[ks] = *(const bf16x8*)&qb[(tokb + qr0B + lq) * 1024 + h * 64 + ks * 32 + g * 8];
        STAGE_K(0, KS[0][0]);
        STAGE_V(0, VS[0][0]);
        __syncthreads();
        for (int it = 0; it < 17; ++it) {
            int buf = it & 1;
            bool pf = it < 16;
            if (pf) {
                STAGE_K(it + 1, KS[0][buf ^ 1]);
                STAGE_V(it + 1, VS[0][buf ^ 1]);
            }
            f32x4 sc[4] = {};
            QK_S(sc, aqB, KS[0][buf]);
            if (it == qbB) MASK_S(sc, qr0B, it);
            EXP_S(sc);
            PV_S(sc, VS[0][buf]);
            __syncthreads();
        }
    } else {
        {
            bf16x8 aqA[2];
#pragma unroll
            for (int ks = 0; ks < 2; ++ks)
                aqA[ks] = *(const bf16x8*)&qb[(tokb + qr0A + lq) * 1024 + h * 64 + ks * 32 + g * 8];
            __syncthreads();
            for (int it = 0; it < TA; ++it) {
                int buf = it & 1;
                if (it == TA - 1) {
                    STAGE_K(17, KS[1][0]);
                    STAGE_V(17, VS[1][0]);
                }
                f32x4 sc[4] = {};
                QK_S(sc, aqA, KS[0][buf]);
                if (it == qbA) MASK_S(sc, qr0A, it);
                EXP_S(sc);
                PV_S(sc, VS[0][buf]);
                __syncthreads();
            }
        }
        {
            float inv = 1.0f / ol[0];
#pragma unroll
            for (int dt = 0; dt < 4; ++dt) {
                bf16x4 ov;
#pragma unroll
                for (int r = 0; r < 4; ++r) ov[r] = (__bf16)(oa[dt][r] * inv);
                *(bf16x4*)&outp[(tokb + qr0A + lq) * 1024 + h * 64 + dt * 16 + g * 4] = ov;
                oa[dt] = (f32x4){0.f, 0.f, 0.f, 0.f};
            }
            ol = (f32x4){0.f, 0.f, 0.f, 0.f};
        }
        {
            bf16x8 aqB[2];
#pragma unroll
            for (int ks = 0; ks < 2; ++ks)
                aqB[ks] = *(const bf16x8*)&qb[(tokb + qr0B + lq) * 1024 + h * 64 + ks * 32 + g * 8];
            int cnt = 16 - TA;
            for (int j = 0; j < cnt; ++j) {
                int buf = j & 1;
                if (j + 1 < cnt) {
                    STAGE_K(17 + j + 1, KS[1][buf ^ 1]);
                    STAGE_V(17 + j + 1, VS[1][buf ^ 1]);
                }
                f32x4 sc[4] = {};
                int kb64 = 17 + j;
                QK_S(sc, aqB, KS[1][buf]);
                if (kb64 == qbB) MASK_S(sc, qr0B, kb64);
                EXP_S(sc);
                PV_S(sc, VS[1][buf]);
                __syncthreads();
            }
        }
        __syncthreads();
    }

    float* mrg_oa = (float*)KS[1];
    float* mrg_ol = (float*)VS[1];
    if (grp == 1) {
#pragma unroll
        for (int dt = 0; dt < 4; ++dt)
#pragma unroll
            for (int r = 0; r < 4; ++r) mrg_oa[tg * 16 + dt * 4 + r] = oa[dt][r];
        mrg_ol[tg] = ol[0];
    }
    __syncthreads();
    if (grp == 0) {
        float l = ol[0] + mrg_ol[tg];
        float inv = 1.0f / l;
#pragma unroll
        for (int dt = 0; dt < 4; ++dt) {
            bf16x4 ov;
#pragma unroll
            for (int r = 0; r < 4; ++r)
                ov[r] = (__bf16)((oa[dt][r] + mrg_oa[tg * 16 + dt * 4 + r]) * inv);
            *(bf16x4*)&outp[(tokb + qr0B + lq) * 1024 + h * 64 + dt * 16 + g * 4] = ov;
        }
    }
#undef STAGE_K
#undef STAGE_V
#undef QK_S
#undef MASK_S
#undef EXP_S
#undef PV_S
}

// ---------------- launch ----------------
extern "C" void kernel_launch(void* const* d_in, const int* in_sizes, int n_in,
                              void* d_out, int out_size, void* d_ws, size_t ws_size,
                              hipStream_t stream) {
    const float* x       = (const float*)d_in[0];
    const float* cosv    = (const float*)d_in[1];
    const float* sinv    = (const float*)d_in[2];
    const float* wq      = (const float*)d_in[4];
    const float* wk      = (const float*)d_in[5];
    const float* wv      = (const float*)d_in[6];
    const float* wo      = (const float*)d_in[7];
    const float* wgate   = (const float*)d_in[8];
    const float* wup     = (const float*)d_in[9];
    const float* wdown   = (const float*)d_in[10];
    const float* norm1   = (const float*)d_in[11];
    const float* norm2   = (const float*)d_in[12];
    const float* ls_attn = (const float*)d_in[13];
    const float* ls_mlp  = (const float*)d_in[14];

    char* ws = (char*)d_ws;
    __bf16* wqkvT = (__bf16*)(ws + OFF_WQKVT);
    __bf16* woT   = (__bf16*)(ws + OFF_WOT);
    __bf16* wguT  = (__bf16*)(ws + OFF_WGUT);
    __bf16* wdT   = (__bf16*)(ws + OFF_WDT);
    __bf16* hb    = (__bf16*)(ws + OFF_HB);
    __bf16* qbuf  = (__bf16*)(ws + OFF_QB);
    __bf16* kbuf  = (__bf16*)(ws + OFF_KB);
    __bf16* vtbuf = (__bf16*)(ws + OFF_H2);     // vtb during attn
    __bf16* attnb = (__bf16*)(ws + OFF_ATTN);
    __bf16* h2b   = (__bf16*)(ws + OFF_H2);     // bf16 h2 after attn (vtb dead)
    __bf16* gb    = (__bf16*)(ws + OFF_G);
    __bf16* mb    = (__bf16*)(ws + OFF_M);
    float*  outf  = (float*)d_out;

    prep_k<<<7680, 256, 0, stream>>>(
        wq, wk, wv, wo, wgate, wup, wdown, wqkvT, woT, wguT, wdT, x, norm1, hb);
    gemm_bt<1, 128, 128, 64><<<dim3(QKVN / 128, NTOK / 128), 256, 0, stream>>>(
        hb, wqkvT, NTOK, QKVN, 512, qbuf, nullptr, nullptr, nullptr, cosv, sinv, kbuf, vtbuf);
    attn_k<<<dim3(NB * NHEAD, 16), 512, 0, stream>>>(qbuf, kbuf, vtbuf, attnb);
    gemm_bt<4, 64, 64, 128><<<dim3(HIDD / 64, NTOK / 64), 256, 0, stream>>>(
        attnb, woT, NTOK, HIDD, 1024, h2b, nullptr, x, ls_attn, nullptr, nullptr, nullptr, nullptr);
    rmsnorm_bk<<<NTOK, 256, 0, stream>>>(h2b, norm2, gb);
    gemm_bt<3, 128, 128, 64><<<dim3(GUN / 128, NTOK / 128), 256, 0, stream>>>(
        gb, wguT, NTOK, GUN, 512, mb, nullptr, nullptr, nullptr, nullptr, nullptr, nullptr, nullptr);
    gemm_bt<5, 64, 64, 128><<<dim3(HIDD / 64, NTOK / 64), 256, 0, stream>>>(
        mb, wdT, NTOK, HIDD, 1024, h2b, outf, nullptr, ls_mlp, nullptr, nullptr, nullptr, nullptr);
}

// Round 20
// 103.749 us; speedup vs baseline: 1.4452x; 1.0107x over previous
//
#include <hip/hip_runtime.h>
#include <hip/hip_bf16.h>

typedef __bf16 bf16x8 __attribute__((ext_vector_type(8)));
typedef __bf16 bf16x4 __attribute__((ext_vector_type(4)));
typedef float f32x4 __attribute__((ext_vector_type(4)));

#define SEQ   2048
#define NB    2
#define NTOK  4096
#define HIDD  512
#define NHEAD 16
#define DHEAD 64
#define QKVN  3072
#define GUN   2048

// workspace layout (bytes)
#define OFF_WQKVT  0u
#define OFF_WOT    3145728u
#define OFF_WGUT   4194304u
#define OFF_WDT    6291456u
#define OFF_HB     7340032u
#define OFF_QB     11534336u                  // qb [4096][1024] bf16
#define OFF_KB     (OFF_QB + 8388608u)        // kb [32][2048][64] bf16
#define OFF_M      (OFF_QB + 16777216u)       // mb (gate*up output)
#define OFF_ATTN   36700160u
#define OFF_H2     45088768u                  // vtb during attn; h2b bf16 after
#define OFF_RV     53477376u                  // rvec [4096] f32 (per-row rms scale)

#define QSCALE 0.1803368801111731f            // 0.125 * log2(e)

#if __has_builtin(__builtin_amdgcn_exp2f)
#define EXP2(x) __builtin_amdgcn_exp2f(x)
#else
#define EXP2(x) exp2f(x)
#endif

typedef unsigned int __attribute__((address_space(1))) as1_uint;
typedef unsigned int __attribute__((address_space(3))) as3_uint;
__device__ __forceinline__ void gload16(const void* g, void* l) {
    __builtin_amdgcn_global_load_lds((const as1_uint*)g, (as3_uint*)l, 16, 0, 0);
}

// ---------------- fused prep: 7 weight transposes + rmsnorm1 ----------------
// wgate/wup rows are pre-scaled by norm2[k]: rmsnorm2 linearity fold.
__global__ __launch_bounds__(256) void prep_k(
    const float* __restrict__ wq, const float* __restrict__ wk,
    const float* __restrict__ wv, const float* __restrict__ wo,
    const float* __restrict__ wg, const float* __restrict__ wu,
    const float* __restrict__ wd,
    __bf16* __restrict__ qkvT, __bf16* __restrict__ woT,
    __bf16* __restrict__ wguT, __bf16* __restrict__ wdT,
    const float* __restrict__ x, const float* __restrict__ norm1,
    const float* __restrict__ norm2, __bf16* __restrict__ hb) {
    __shared__ float t[32][33];
    int bid = blockIdx.x;
    if (bid < 3584) {
        int which = bid >> 9, bx = bid & 511;
        const float* in; __bf16* out; int K, N, mode = 0, phase = 0, nw = 0;
        switch (which) {
            case 0: in = wq; out = qkvT;              K = 512;  N = 1024; break;
            case 1: in = wk; out = qkvT + 1024 * 512; K = 512;  N = 1024; break;
            case 2: in = wv; out = qkvT + 2048 * 512; K = 512;  N = 1024; break;
            case 3: in = wo; out = woT;               K = 1024; N = 512;  break;
            case 4: in = wg; out = wguT;              K = 512;  N = 1024; mode = 1; phase = 0; nw = 1; break;
            case 5: in = wu; out = wguT;              K = 512;  N = 1024; mode = 1; phase = 1; nw = 1; break;
            default: in = wd; out = wdT;              K = 1024; N = 512;  break;
        }
        int ntn = N >> 5;
        int n0 = (bx & (ntn - 1)) * 32;
        int k0 = (bx / ntn) * 32;
        int tx = threadIdx.x & 31, ty = threadIdx.x >> 5;
#pragma unroll
        for (int j = 0; j < 4; ++j)
            t[ty * 4 + j][tx] = in[(size_t)(k0 + ty * 4 + j) * N + n0 + tx];
        __syncthreads();
        float ws = nw ? norm2[k0 + tx] : 1.0f;
#pragma unroll
        for (int j = 0; j < 4; ++j) {
            int n = n0 + ty * 4 + j;
            int row = mode ? (((n >> 4) << 5) + phase * 16 + (n & 15)) : n;
            out[(size_t)row * K + k0 + tx] = (__bf16)(t[tx][ty * 4 + j] * ws);
        }
    } else {
        int row = bid - 3584;
        int tt = threadIdx.x;
        const float* xr = x + (size_t)row * HIDD;
        float2 v = *(const float2*)&xr[tt * 2];
        float ss = v.x * v.x + v.y * v.y;
#pragma unroll
        for (int off = 32; off >= 1; off >>= 1) ss += __shfl_xor(ss, off);
        if ((tt & 63) == 0) t[0][tt >> 6] = ss;
        __syncthreads();
        float tot = t[0][0] + t[0][1] + t[0][2] + t[0][3];
        float r = rsqrtf(tot * (1.0f / HIDD) + 1e-8f);
        hb[(size_t)row * HIDD + tt * 2]     = (__bf16)(v.x * r * norm1[tt * 2]);
        hb[(size_t)row * HIDD + tt * 2 + 1] = (__bf16)(v.y * r * norm1[tt * 2 + 1]);
    }
}

// ---------------- per-row rms scale of h2b: r[row] = rsqrt(mean+eps) ----------------
__global__ __launch_bounds__(64) void rnorm_k(const __bf16* __restrict__ h2,
                                              float* __restrict__ rvec) {
    int row = blockIdx.x;
    int lane = threadIdx.x;
    bf16x8 v = *(const bf16x8*)&h2[(size_t)row * HIDD + lane * 8];
    float ss = 0.0f;
#pragma unroll
    for (int j = 0; j < 8; ++j) { float f = (float)v[j]; ss += f * f; }
#pragma unroll
    for (int off = 32; off >= 1; off >>= 1) ss += __shfl_xor(ss, off);
    if (lane == 0) rvec[row] = rsqrtf(ss * (1.0f / HIDD) + 1e-8f);
}

// ---------------- GEMM: C[M][N] = A[M][K] * Bt[N][K]^T ----------------
// EPI 1: QKV epilogue (rope Q/K compact, fused V transpose+permute).
// EPI 3: per-row scale (rmsnorm fold) then silu(gate)*up.
// EPI 4: bf16 out = f32 resid + acc*scale. EPI 5: f32 out = bf16 resid + acc*scale.
template <int EPI, int TM, int TN, int BK>
__global__ __launch_bounds__(256) void gemm_bt(const __bf16* __restrict__ A,
                                               const __bf16* __restrict__ Bt,
                                               int M, int N, int K,
                                               __bf16* __restrict__ Cb,
                                               float* __restrict__ Cf,
                                               const float* __restrict__ resid,
                                               const float* __restrict__ scale,
                                               const float* __restrict__ cosv,
                                               const float* __restrict__ sinv,
                                               __bf16* __restrict__ kbp,
                                               __bf16* __restrict__ vtbp) {
    __shared__ alignas(16) __bf16 smem[TM * BK + TN * BK];
    __bf16 (*As)[BK] = (__bf16(*)[BK])smem;
    __bf16 (*Bs)[BK] = (__bf16(*)[BK])(smem + TM * BK);
    constexpr int MI = TM / 32, NI = TN / 32;
    constexpr int CPB = BK / 8;
    int nwg = gridDim.x * gridDim.y;
    int bid = blockIdx.y * gridDim.x + blockIdx.x;
    int swz = (bid & 7) * (nwg >> 3) + (bid >> 3);
    int bx = swz % gridDim.x, by = swz / gridDim.x;
    int m0 = by * TM, n0 = bx * TN;
    int tid = threadIdx.x;
    int lane = tid & 63, w = tid >> 6;
    int wm = (w >> 1) * (TM / 2), wn = (w & 1) * (TN / 2);
    int lr = lane & 15, lkg = lane >> 4;
    f32x4 acc[MI][NI] = {};
    int nkt = K / BK;
    for (int kt = 0; kt < nkt; ++kt) {
        __syncthreads();
#pragma unroll
        for (int i = 0; i < (TM * BK) / 2048; ++i) {
            int c = i * 256 + tid;
            int row = c / CPB, ch = c % CPB;
            gload16(&A[(size_t)(m0 + row) * K + kt * BK + ((ch ^ (row & 7)) << 3)],
                    (__bf16*)As + c * 8);
        }
#pragma unroll
        for (int i = 0; i < (TN * BK) / 2048; ++i) {
            int c = i * 256 + tid;
            int row = c / CPB, ch = c % CPB;
            gload16(&Bt[(size_t)(n0 + row) * K + kt * BK + ((ch ^ (row & 7)) << 3)],
                    (__bf16*)Bs + c * 8);
        }
        __syncthreads();
#pragma unroll
        for (int kk = 0; kk < BK / 32; ++kk) {
            bf16x8 af[MI], bfv[NI];
#pragma unroll
            for (int mi = 0; mi < MI; ++mi) {
                int row = wm + mi * 16 + lr;
                af[mi] = *(const bf16x8*)&As[row][(((kk * 4 + lkg) ^ (row & 7)) << 3)];
            }
#pragma unroll
            for (int ni = 0; ni < NI; ++ni) {
                int row = wn + ni * 16 + lr;
                bfv[ni] = *(const bf16x8*)&Bs[row][(((kk * 4 + lkg) ^ (row & 7)) << 3)];
            }
#pragma unroll
            for (int mi = 0; mi < MI; ++mi)
#pragma unroll
                for (int ni = 0; ni < NI; ++ni)
                    acc[mi][ni] = __builtin_amdgcn_mfma_f32_16x16x32_bf16(
                        af[mi], bfv[ni], acc[mi][ni], 0, 0, 0);
        }
    }
    if (EPI == 1) {
        int col0 = n0 + wn;
        int hh = (col0 >> 6) & 15;
        if (col0 < 1024) {                  // Q: rope * QSCALE -> qb
#pragma unroll
            for (int mi = 0; mi < MI; ++mi)
#pragma unroll
                for (int r = 0; r < 4; ++r) {
                    int row = m0 + wm + mi * 16 + lkg * 4 + r;
                    int s = row & (SEQ - 1);
#pragma unroll
                    for (int ni = 0; ni < 2; ++ni) {
                        float v1 = acc[mi][ni][r], v2 = acc[mi][ni + 2][r];
                        int d = ni * 16 + lr;
                        float c = cosv[s * 32 + d], sn = sinv[s * 32 + d];
                        size_t i1 = (size_t)row * 1024 + col0 + d;
                        Cb[i1]      = (__bf16)((v1 * c - v2 * sn) * QSCALE);
                        Cb[i1 + 32] = (__bf16)((v2 * c + v1 * sn) * QSCALE);
                    }
                }
        } else if (col0 < 2048) {           // K: rope -> kb compact
#pragma unroll
            for (int mi = 0; mi < MI; ++mi)
#pragma unroll
                for (int r = 0; r < 4; ++r) {
                    int row = m0 + wm + mi * 16 + lkg * 4 + r;
                    int s = row & (SEQ - 1);
                    size_t hdr = ((size_t)((row >> 11) * 16 + hh) * SEQ + s) * 64;
#pragma unroll
                    for (int ni = 0; ni < 2; ++ni) {
                        float v1 = acc[mi][ni][r], v2 = acc[mi][ni + 2][r];
                        int d = ni * 16 + lr;
                        float c = cosv[s * 32 + d], sn = sinv[s * 32 + d];
                        kbp[hdr + d]      = (__bf16)(v1 * c - v2 * sn);
                        kbp[hdr + d + 32] = (__bf16)(v2 * c + v1 * sn);
                    }
                }
        } else {                            // V: fused transpose+permute -> vtb
            __bf16* tr = smem;
            int bh0 = (m0 >> 11) * 16 + ((n0 >> 6) & 15);
#pragma unroll
            for (int p = 0; p < 2; ++p) {
                __syncthreads();
                if ((wm >> 6) == p) {
#pragma unroll
                    for (int mi = 0; mi < MI; ++mi)
#pragma unroll
                        for (int ni = 0; ni < NI; ++ni)
#pragma unroll
                            for (int r = 0; r < 4; ++r) {
                                int row_l = mi * 16 + lkg * 4 + r;
                                int col_l = wn + ni * 16 + lr;
                                tr[col_l * 66 + row_l] = (__bf16)acc[mi][ni][r];
                            }
                }
                __syncthreads();
                int s0 = (m0 & (SEQ - 1)) + p * 64;
#pragma unroll
                for (int i = 0; i < 4; ++i) {
                    int c = i * 256 + tid;
                    int col_l = c >> 3, cc = c & 7;
                    int dv = col_l & 63, h3 = col_l >> 6;
                    int K0 = 32 * (cc >> 2) + 4 * (cc & 3);
                    __bf16 outv[8];
#pragma unroll
                    for (int j = 0; j < 4; ++j) outv[j]     = tr[col_l * 66 + K0 + j];
#pragma unroll
                    for (int j = 0; j < 4; ++j) outv[4 + j] = tr[col_l * 66 + K0 + 16 + j];
                    *(uint4*)&vtbp[((size_t)(bh0 + h3) * 64 + dv) * SEQ + s0 + cc * 8] =
                        *(uint4*)outv;
                }
            }
        }
    } else if (EPI == 3) {                  // per-row rms scale + silu(g)*u
#pragma unroll
        for (int mi = 0; mi < MI; ++mi)
#pragma unroll
            for (int r = 0; r < 4; ++r) {
                int row = m0 + wm + mi * 16 + lkg * 4 + r;
                float rr = scale[row];
#pragma unroll
                for (int ni = 0; ni < 4; ni += 2) {
                    float g = acc[mi][ni][r] * rr, u = acc[mi][ni + 1][r] * rr;
                    float mv = (g / (1.0f + __expf(-g))) * u;
                    int j = (((n0 + wn + ni * 16) >> 5) << 4) + lr;
                    Cb[(size_t)row * 1024 + j] = (__bf16)mv;
                }
            }
    } else if (EPI == 4) {                  // bf16 out = f32 resid + acc*scale
#pragma unroll
        for (int mi = 0; mi < MI; ++mi)
#pragma unroll
            for (int ni = 0; ni < NI; ++ni)
#pragma unroll
                for (int r = 0; r < 4; ++r) {
                    int row = m0 + wm + mi * 16 + lkg * 4 + r;
                    int col = n0 + wn + ni * 16 + lr;
                    size_t idx = (size_t)row * N + col;
                    Cb[idx] = (__bf16)(resid[idx] + acc[mi][ni][r] * scale[col]);
                }
    } else if (EPI == 5) {                  // f32 out = bf16 resid(Cb) + acc*scale
        const __bf16* rb = (const __bf16*)Cb;
#pragma unroll
        for (int mi = 0; mi < MI; ++mi)
#pragma unroll
            for (int ni = 0; ni < NI; ++ni)
#pragma unroll
                for (int r = 0; r < 4; ++r) {
                    int row = m0 + wm + mi * 16 + lkg * 4 + r;
                    int col = n0 + wn + ni * 16 + lr;
                    size_t idx = (size_t)row * N + col;
                    Cf[idx] = (float)rb[idx] + acc[mi][ni][r] * scale[col];
                }
    }
}

// ---------------- causal flash attention: dual wave-group, coalesced staging ----------------
__global__ __launch_bounds__(512, 4) void attn_k(const __bf16* __restrict__ qb,
                                                 const __bf16* __restrict__ kb,
                                                 const __bf16* __restrict__ vtb,
                                                 __bf16* __restrict__ outp) {
    __shared__ alignas(16) __bf16 KS[2][2][4096];
    __shared__ alignas(16) __bf16 VS[2][2][4096];
    int bh = blockIdx.x;
    int b = bh >> 4, h = bh & 15;
    int y = blockIdx.y;
    int qbA = y, qbB = 31 - y;
    int TA = y + 1;
    int tid = threadIdx.x;
    int grp = tid >> 8;
    int tg  = tid & 255;
    int lane = tid & 63, wg = tg >> 6;
    int lq = lane & 15, g = lane >> 4;
    size_t tokb = (size_t)b * SEQ;
    int qr0A = qbA * 64 + wg * 16, qr0B = qbB * 64 + wg * 16;

    bf16x8 ones8;
#pragma unroll
    for (int e = 0; e < 8; ++e) ones8[e] = (__bf16)1.0f;

    f32x4 oa[4] = {};
    f32x4 ol = {};

#define STAGE_K(kbn, kdst)                                                                         \
    {                                                                                              \
        _Pragma("unroll")                                                                          \
        for (int i = 0; i < 2; ++i) {                                                              \
            int c = i * 256 + tg;                                                                  \
            int kr = c >> 3, ch = c & 7;                                                           \
            gload16(&kb[((size_t)bh * SEQ + (kbn) * 64 + kr) * 64 + ((ch ^ (kr & 7)) << 3)],       \
                    (kdst) + c * 8);                                                               \
        }                                                                                          \
    }

#define STAGE_V(kbn, vdst)                                                                         \
    {                                                                                              \
        _Pragma("unroll")                                                                          \
        for (int i = 0; i < 2; ++i) {                                                              \
            int c = i * 256 + tg;                                                                  \
            int vr = c >> 3, ch = c & 7;                                                           \
            gload16(&vtb[((size_t)bh * 64 + vr) * SEQ + (kbn) * 64 + ((ch ^ (vr & 7)) << 3)],      \
                    (vdst) + c * 8);                                                               \
        }                                                                                          \
    }

#define QK_S(sc, aq, ksrc)                                                                         \
    {                                                                                              \
        __builtin_amdgcn_s_setprio(1);                                                             \
        _Pragma("unroll")                                                                          \
        for (int jt = 0; jt < 4; ++jt)                                                             \
            _Pragma("unroll")                                                                      \
            for (int ks = 0; ks < 2; ++ks) {                                                       \
                bf16x8 bk = *(const bf16x8*)&(ksrc)[(jt * 16 + lq) * 64 + (((ks * 4 + g) ^ (lq & 7)) << 3)]; \
                sc[jt] = __builtin_amdgcn_mfma_f32_16x16x32_bf16(bk, aq[ks], sc[jt], 0, 0, 0);     \
            }                                                                                      \
        __builtin_amdgcn_s_setprio(0);                                                             \
    }

#define MASK_S(sc, qr0_t, kb64)                                                                    \
    {                                                                                              \
        int qabs = (qr0_t) + lq;                                                                   \
        _Pragma("unroll")                                                                          \
        for (int jt = 0; jt < 4; ++jt)                                                             \
            _Pragma("unroll")                                                                      \
            for (int r = 0; r < 4; ++r) {                                                          \
                int key = (kb64) * 64 + jt * 16 + g * 4 + r;                                       \
                if (key > qabs) sc[jt][r] = -1e9f;                                                 \
            }                                                                                      \
    }

#define EXP_S(sc)                                                                                  \
    _Pragma("unroll")                                                                              \
    for (int jt = 0; jt < 4; ++jt)                                                                 \
        _Pragma("unroll")                                                                          \
        for (int r = 0; r < 4; ++r) sc[jt][r] = EXP2(sc[jt][r]);

#define PV_S(sc, vsrc)                                                                             \
    {                                                                                              \
        __builtin_amdgcn_s_setprio(1);                                                             \
        _Pragma("unroll")                                                                          \
        for (int ks2 = 0; ks2 < 2; ++ks2) {                                                        \
            bf16x8 pfv;                                                                            \
            _Pragma("unroll")                                                                      \
            for (int e = 0; e < 4; ++e) {                                                          \
                pfv[e]     = (__bf16)sc[2 * ks2][e];                                               \
                pfv[e + 4] = (__bf16)sc[2 * ks2 + 1][e];                                           \
            }                                                                                      \
            ol = __builtin_amdgcn_mfma_f32_16x16x32_bf16(ones8, pfv, ol, 0, 0, 0);                 \
            _Pragma("unroll")                                                                      \
            for (int dt = 0; dt < 4; ++dt) {                                                       \
                bf16x8 av = *(const bf16x8*)&(vsrc)[(dt * 16 + lq) * 64 + (((ks2 * 4 + g) ^ (lq & 7)) << 3)]; \
                oa[dt] = __builtin_amdgcn_mfma_f32_16x16x32_bf16(av, pfv, oa[dt], 0, 0, 0);        \
            }                                                                                      \
        }                                                                                          \
        __builtin_amdgcn_s_setprio(0);                                                             \
    }

    if (grp == 0) {
        bf16x8 aqB[2];
#pragma unroll
        for (int ks = 0; ks < 2; ++ks)
            aqB[ks] = *(const bf16x8*)&qb[(tokb + qr0B + lq) * 1024 + h * 64 + ks * 32 + g * 8];
        STAGE_K(0, KS[0][0]);
        STAGE_V(0, VS[0][0]);
        __syncthreads();
        for (int it = 0; it < 17; ++it) {
            int buf = it & 1;
            bool pf = it < 16;
            if (pf) {
                STAGE_K(it + 1, KS[0][buf ^ 1]);
                STAGE_V(it + 1, VS[0][buf ^ 1]);
            }
            f32x4 sc[4] = {};
            QK_S(sc, aqB, KS[0][buf]);
            if (it == qbB) MASK_S(sc, qr0B, it);
            EXP_S(sc);
            PV_S(sc, VS[0][buf]);
            __syncthreads();
        }
    } else {
        {
            bf16x8 aqA[2];
#pragma unroll
            for (int ks = 0; ks < 2; ++ks)
                aqA[ks] = *(const bf16x8*)&qb[(tokb + qr0A + lq) * 1024 + h * 64 + ks * 32 + g * 8];
            __syncthreads();
            for (int it = 0; it < TA; ++it) {
                int buf = it & 1;
                if (it == TA - 1) {
                    STAGE_K(17, KS[1][0]);
                    STAGE_V(17, VS[1][0]);
                }
                f32x4 sc[4] = {};
                QK_S(sc, aqA, KS[0][buf]);
                if (it == qbA) MASK_S(sc, qr0A, it);
                EXP_S(sc);
                PV_S(sc, VS[0][buf]);
                __syncthreads();
            }
        }
        {
            float inv = 1.0f / ol[0];
#pragma unroll
            for (int dt = 0; dt < 4; ++dt) {
                bf16x4 ov;
#pragma unroll
                for (int r = 0; r < 4; ++r) ov[r] = (__bf16)(oa[dt][r] * inv);
                *(bf16x4*)&outp[(tokb + qr0A + lq) * 1024 + h * 64 + dt * 16 + g * 4] = ov;
                oa[dt] = (f32x4){0.f, 0.f, 0.f, 0.f};
            }
            ol = (f32x4){0.f, 0.f, 0.f, 0.f};
        }
        {
            bf16x8 aqB[2];
#pragma unroll
            for (int ks = 0; ks < 2; ++ks)
                aqB[ks] = *(const bf16x8*)&qb[(tokb + qr0B + lq) * 1024 + h * 64 + ks * 32 + g * 8];
            int cnt = 16 - TA;
            for (int j = 0; j < cnt; ++j) {
                int buf = j & 1;
                if (j + 1 < cnt) {
                    STAGE_K(17 + j + 1, KS[1][buf ^ 1]);
                    STAGE_V(17 + j + 1, VS[1][buf ^ 1]);
                }
                f32x4 sc[4] = {};
                int kb64 = 17 + j;
                QK_S(sc, aqB, KS[1][buf]);
                if (kb64 == qbB) MASK_S(sc, qr0B, kb64);
                EXP_S(sc);
                PV_S(sc, VS[1][buf]);
                __syncthreads();
            }
        }
        __syncthreads();
    }

    float* mrg_oa = (float*)KS[1];
    float* mrg_ol = (float*)VS[1];
    if (grp == 1) {
#pragma unroll
        for (int dt = 0; dt < 4; ++dt)
#pragma unroll
            for (int r = 0; r < 4; ++r) mrg_oa[tg * 16 + dt * 4 + r] = oa[dt][r];
        mrg_ol[tg] = ol[0];
    }
    __syncthreads();
    if (grp == 0) {
        float l = ol[0] + mrg_ol[tg];
        float inv = 1.0f / l;
#pragma unroll
        for (int dt = 0; dt < 4; ++dt) {
            bf16x4 ov;
#pragma unroll
            for (int r = 0; r < 4; ++r)
                ov[r] = (__bf16)((oa[dt][r] + mrg_oa[tg * 16 + dt * 4 + r]) * inv);
            *(bf16x4*)&outp[(tokb + qr0B + lq) * 1024 + h * 64 + dt * 16 + g * 4] = ov;
        }
    }
#undef STAGE_K
#undef STAGE_V
#undef QK_S
#undef MASK_S
#undef EXP_S
#undef PV_S
}

// ---------------- launch ----------------
extern "C" void kernel_launch(void* const* d_in, const int* in_sizes, int n_in,
                              void* d_out, int out_size, void* d_ws, size_t ws_size,
                              hipStream_t stream) {
    const float* x       = (const float*)d_in[0];
    const float* cosv    = (const float*)d_in[1];
    const float* sinv    = (const float*)d_in[2];
    const float* wq      = (const float*)d_in[4];
    const float* wk      = (const float*)d_in[5];
    const float* wv      = (const float*)d_in[6];
    const float* wo      = (const float*)d_in[7];
    const float* wgate   = (const float*)d_in[8];
    const float* wup     = (const float*)d_in[9];
    const float* wdown   = (const float*)d_in[10];
    const float* norm1   = (const float*)d_in[11];
    const float* norm2   = (const float*)d_in[12];
    const float* ls_attn = (const float*)d_in[13];
    const float* ls_mlp  = (const float*)d_in[14];

    char* ws = (char*)d_ws;
    __bf16* wqkvT = (__bf16*)(ws + OFF_WQKVT);
    __bf16* woT   = (__bf16*)(ws + OFF_WOT);
    __bf16* wguT  = (__bf16*)(ws + OFF_WGUT);
    __bf16* wdT   = (__bf16*)(ws + OFF_WDT);
    __bf16* hb    = (__bf16*)(ws + OFF_HB);
    __bf16* qbuf  = (__bf16*)(ws + OFF_QB);
    __bf16* kbuf  = (__bf16*)(ws + OFF_KB);
    __bf16* vtbuf = (__bf16*)(ws + OFF_H2);     // vtb during attn
    __bf16* attnb = (__bf16*)(ws + OFF_ATTN);
    __bf16* h2b   = (__bf16*)(ws + OFF_H2);     // bf16 h2 after attn (vtb dead)
    float*  rvec  = (float*)(ws + OFF_RV);
    __bf16* mb    = (__bf16*)(ws + OFF_M);
    float*  outf  = (float*)d_out;

    prep_k<<<7680, 256, 0, stream>>>(
        wq, wk, wv, wo, wgate, wup, wdown, wqkvT, woT, wguT, wdT, x, norm1, norm2, hb);
    gemm_bt<1, 128, 128, 64><<<dim3(QKVN / 128, NTOK / 128), 256, 0, stream>>>(
        hb, wqkvT, NTOK, QKVN, 512, qbuf, nullptr, nullptr, nullptr, cosv, sinv, kbuf, vtbuf);
    attn_k<<<dim3(NB * NHEAD, 16), 512, 0, stream>>>(qbuf, kbuf, vtbuf, attnb);
    gemm_bt<4, 64, 64, 128><<<dim3(HIDD / 64, NTOK / 64), 256, 0, stream>>>(
        attnb, woT, NTOK, HIDD, 1024, h2b, nullptr, x, ls_attn, nullptr, nullptr, nullptr, nullptr);
    rnorm_k<<<NTOK, 64, 0, stream>>>(h2b, rvec);
    gemm_bt<3, 128, 128, 64><<<dim3(GUN / 128, NTOK / 128), 256, 0, stream>>>(
        h2b, wguT, NTOK, GUN, 512, mb, nullptr, nullptr, rvec, nullptr, nullptr, nullptr, nullptr);
    gemm_bt<5, 64, 64, 128><<<dim3(HIDD / 64, NTOK / 64), 256, 0, stream>>>(
        mb, wdT, NTOK, HIDD, 1024, h2b, outf, nullptr, ls_mlp, nullptr, nullptr, nullptr, nullptr);
}

// Round 21
// 103.189 us; speedup vs baseline: 1.4530x; 1.0054x over previous
//
#include <hip/hip_runtime.h>
#include <hip/hip_bf16.h>

typedef __bf16 bf16x8 __attribute__((ext_vector_type(8)));
typedef __bf16 bf16x4 __attribute__((ext_vector_type(4)));
typedef float f32x4 __attribute__((ext_vector_type(4)));

#define SEQ   2048
#define NB    2
#define NTOK  4096
#define HIDD  512
#define NHEAD 16
#define DHEAD 64
#define QKVN  3072
#define GUN   2048

// workspace layout (bytes)
#define OFF_WQKVT  0u
#define OFF_WOT    3145728u
#define OFF_WGUT   4194304u
#define OFF_WDT    6291456u
#define OFF_HB     7340032u
#define OFF_QB     11534336u                  // qb [4096][1024] bf16
#define OFF_KB     (OFF_QB + 8388608u)        // kb [32][2048][64] bf16
#define OFF_M      (OFF_QB + 16777216u)       // mb (gate*up output)
#define OFF_ATTN   36700160u
#define OFF_H2     45088768u                  // vtb during attn; h2b bf16 after
#define OFF_RV     53477376u                  // rvec [4096] f32 (per-row sum of squares)

#define QSCALE 0.1803368801111731f            // 0.125 * log2(e)

#if __has_builtin(__builtin_amdgcn_exp2f)
#define EXP2(x) __builtin_amdgcn_exp2f(x)
#else
#define EXP2(x) exp2f(x)
#endif

typedef unsigned int __attribute__((address_space(1))) as1_uint;
typedef unsigned int __attribute__((address_space(3))) as3_uint;
__device__ __forceinline__ void gload16(const void* g, void* l) {
    __builtin_amdgcn_global_load_lds((const as1_uint*)g, (as3_uint*)l, 16, 0, 0);
}

// ---------------- fused prep: 7 weight transposes + rmsnorm1 + rvec zero ----------------
// wgate/wup rows pre-scaled by norm2[k] (rmsnorm2 linearity fold).
__global__ __launch_bounds__(256) void prep_k(
    const float* __restrict__ wq, const float* __restrict__ wk,
    const float* __restrict__ wv, const float* __restrict__ wo,
    const float* __restrict__ wg, const float* __restrict__ wu,
    const float* __restrict__ wd,
    __bf16* __restrict__ qkvT, __bf16* __restrict__ woT,
    __bf16* __restrict__ wguT, __bf16* __restrict__ wdT,
    const float* __restrict__ x, const float* __restrict__ norm1,
    const float* __restrict__ norm2, __bf16* __restrict__ hb,
    float* __restrict__ rvec) {
    __shared__ float t[32][33];
    int bid = blockIdx.x;
    if (bid < 3584) {
        int which = bid >> 9, bx = bid & 511;
        const float* in; __bf16* out; int K, N, mode = 0, phase = 0, nw = 0;
        switch (which) {
            case 0: in = wq; out = qkvT;              K = 512;  N = 1024; break;
            case 1: in = wk; out = qkvT + 1024 * 512; K = 512;  N = 1024; break;
            case 2: in = wv; out = qkvT + 2048 * 512; K = 512;  N = 1024; break;
            case 3: in = wo; out = woT;               K = 1024; N = 512;  break;
            case 4: in = wg; out = wguT;              K = 512;  N = 1024; mode = 1; phase = 0; nw = 1; break;
            case 5: in = wu; out = wguT;              K = 512;  N = 1024; mode = 1; phase = 1; nw = 1; break;
            default: in = wd; out = wdT;              K = 1024; N = 512;  break;
        }
        int ntn = N >> 5;
        int n0 = (bx & (ntn - 1)) * 32;
        int k0 = (bx / ntn) * 32;
        int tx = threadIdx.x & 31, ty = threadIdx.x >> 5;
#pragma unroll
        for (int j = 0; j < 4; ++j)
            t[ty * 4 + j][tx] = in[(size_t)(k0 + ty * 4 + j) * N + n0 + tx];
        __syncthreads();
        float ws = nw ? norm2[k0 + tx] : 1.0f;
#pragma unroll
        for (int j = 0; j < 4; ++j) {
            int n = n0 + ty * 4 + j;
            int row = mode ? (((n >> 4) << 5) + phase * 16 + (n & 15)) : n;
            out[(size_t)row * K + k0 + tx] = (__bf16)(t[tx][ty * 4 + j] * ws);
        }
    } else {
        int row = bid - 3584;
        int tt = threadIdx.x;
        if (tt == 0) rvec[row] = 0.0f;      // zero the Σh² accumulator each call
        const float* xr = x + (size_t)row * HIDD;
        float2 v = *(const float2*)&xr[tt * 2];
        float ss = v.x * v.x + v.y * v.y;
#pragma unroll
        for (int off = 32; off >= 1; off >>= 1) ss += __shfl_xor(ss, off);
        if ((tt & 63) == 0) t[0][tt >> 6] = ss;
        __syncthreads();
        float tot = t[0][0] + t[0][1] + t[0][2] + t[0][3];
        float r = rsqrtf(tot * (1.0f / HIDD) + 1e-8f);
        hb[(size_t)row * HIDD + tt * 2]     = (__bf16)(v.x * r * norm1[tt * 2]);
        hb[(size_t)row * HIDD + tt * 2 + 1] = (__bf16)(v.y * r * norm1[tt * 2 + 1]);
    }
}

// ---------------- GEMM: C[M][N] = A[M][K] * Bt[N][K]^T ----------------
// EPI 1: QKV epilogue (rope Q/K compact, fused V transpose+permute).
// EPI 3: rr = rsqrt(rvec[row]/512+eps) fold, then silu(gate)*up.
// EPI 4: bf16 out = f32 resid + acc*scale; fused Σh² atomicAdd into Cf(=rvec).
// EPI 5: f32 out = bf16 resid(Cb) + acc*scale.
template <int EPI, int TM, int TN, int BK>
__global__ __launch_bounds__(256) void gemm_bt(const __bf16* __restrict__ A,
                                               const __bf16* __restrict__ Bt,
                                               int M, int N, int K,
                                               __bf16* __restrict__ Cb,
                                               float* __restrict__ Cf,
                                               const float* __restrict__ resid,
                                               const float* __restrict__ scale,
                                               const float* __restrict__ cosv,
                                               const float* __restrict__ sinv,
                                               __bf16* __restrict__ kbp,
                                               __bf16* __restrict__ vtbp) {
    __shared__ alignas(16) __bf16 smem[TM * BK + TN * BK];
    __bf16 (*As)[BK] = (__bf16(*)[BK])smem;
    __bf16 (*Bs)[BK] = (__bf16(*)[BK])(smem + TM * BK);
    constexpr int MI = TM / 32, NI = TN / 32;
    constexpr int CPB = BK / 8;
    int nwg = gridDim.x * gridDim.y;
    int bid = blockIdx.y * gridDim.x + blockIdx.x;
    int swz = (bid & 7) * (nwg >> 3) + (bid >> 3);
    int bx = swz % gridDim.x, by = swz / gridDim.x;
    int m0 = by * TM, n0 = bx * TN;
    int tid = threadIdx.x;
    int lane = tid & 63, w = tid >> 6;
    int wm = (w >> 1) * (TM / 2), wn = (w & 1) * (TN / 2);
    int lr = lane & 15, lkg = lane >> 4;
    f32x4 acc[MI][NI] = {};
    int nkt = K / BK;
    for (int kt = 0; kt < nkt; ++kt) {
        __syncthreads();
#pragma unroll
        for (int i = 0; i < (TM * BK) / 2048; ++i) {
            int c = i * 256 + tid;
            int row = c / CPB, ch = c % CPB;
            gload16(&A[(size_t)(m0 + row) * K + kt * BK + ((ch ^ (row & 7)) << 3)],
                    (__bf16*)As + c * 8);
        }
#pragma unroll
        for (int i = 0; i < (TN * BK) / 2048; ++i) {
            int c = i * 256 + tid;
            int row = c / CPB, ch = c % CPB;
            gload16(&Bt[(size_t)(n0 + row) * K + kt * BK + ((ch ^ (row & 7)) << 3)],
                    (__bf16*)Bs + c * 8);
        }
        __syncthreads();
#pragma unroll
        for (int kk = 0; kk < BK / 32; ++kk) {
            bf16x8 af[MI], bfv[NI];
#pragma unroll
            for (int mi = 0; mi < MI; ++mi) {
                int row = wm + mi * 16 + lr;
                af[mi] = *(const bf16x8*)&As[row][(((kk * 4 + lkg) ^ (row & 7)) << 3)];
            }
#pragma unroll
            for (int ni = 0; ni < NI; ++ni) {
                int row = wn + ni * 16 + lr;
                bfv[ni] = *(const bf16x8*)&Bs[row][(((kk * 4 + lkg) ^ (row & 7)) << 3)];
            }
#pragma unroll
            for (int mi = 0; mi < MI; ++mi)
#pragma unroll
                for (int ni = 0; ni < NI; ++ni)
                    acc[mi][ni] = __builtin_amdgcn_mfma_f32_16x16x32_bf16(
                        af[mi], bfv[ni], acc[mi][ni], 0, 0, 0);
        }
    }
    if (EPI == 1) {
        int col0 = n0 + wn;
        int hh = (col0 >> 6) & 15;
        if (col0 < 1024) {                  // Q: rope * QSCALE -> qb
#pragma unroll
            for (int mi = 0; mi < MI; ++mi)
#pragma unroll
                for (int r = 0; r < 4; ++r) {
                    int row = m0 + wm + mi * 16 + lkg * 4 + r;
                    int s = row & (SEQ - 1);
#pragma unroll
                    for (int ni = 0; ni < 2; ++ni) {
                        float v1 = acc[mi][ni][r], v2 = acc[mi][ni + 2][r];
                        int d = ni * 16 + lr;
                        float c = cosv[s * 32 + d], sn = sinv[s * 32 + d];
                        size_t i1 = (size_t)row * 1024 + col0 + d;
                        Cb[i1]      = (__bf16)((v1 * c - v2 * sn) * QSCALE);
                        Cb[i1 + 32] = (__bf16)((v2 * c + v1 * sn) * QSCALE);
                    }
                }
        } else if (col0 < 2048) {           // K: rope -> kb compact
#pragma unroll
            for (int mi = 0; mi < MI; ++mi)
#pragma unroll
                for (int r = 0; r < 4; ++r) {
                    int row = m0 + wm + mi * 16 + lkg * 4 + r;
                    int s = row & (SEQ - 1);
                    size_t hdr = ((size_t)((row >> 11) * 16 + hh) * SEQ + s) * 64;
#pragma unroll
                    for (int ni = 0; ni < 2; ++ni) {
                        float v1 = acc[mi][ni][r], v2 = acc[mi][ni + 2][r];
                        int d = ni * 16 + lr;
                        float c = cosv[s * 32 + d], sn = sinv[s * 32 + d];
                        kbp[hdr + d]      = (__bf16)(v1 * c - v2 * sn);
                        kbp[hdr + d + 32] = (__bf16)(v2 * c + v1 * sn);
                    }
                }
        } else {                            // V: fused transpose+permute -> vtb
            __bf16* tr = smem;
            int bh0 = (m0 >> 11) * 16 + ((n0 >> 6) & 15);
#pragma unroll
            for (int p = 0; p < 2; ++p) {
                __syncthreads();
                if ((wm >> 6) == p) {
#pragma unroll
                    for (int mi = 0; mi < MI; ++mi)
#pragma unroll
                        for (int ni = 0; ni < NI; ++ni)
#pragma unroll
                            for (int r = 0; r < 4; ++r) {
                                int row_l = mi * 16 + lkg * 4 + r;
                                int col_l = wn + ni * 16 + lr;
                                tr[col_l * 66 + row_l] = (__bf16)acc[mi][ni][r];
                            }
                }
                __syncthreads();
                int s0 = (m0 & (SEQ - 1)) + p * 64;
#pragma unroll
                for (int i = 0; i < 4; ++i) {
                    int c = i * 256 + tid;
                    int col_l = c >> 3, cc = c & 7;
                    int dv = col_l & 63, h3 = col_l >> 6;
                    int K0 = 32 * (cc >> 2) + 4 * (cc & 3);
                    __bf16 outv[8];
#pragma unroll
                    for (int j = 0; j < 4; ++j) outv[j]     = tr[col_l * 66 + K0 + j];
#pragma unroll
                    for (int j = 0; j < 4; ++j) outv[4 + j] = tr[col_l * 66 + K0 + 16 + j];
                    *(uint4*)&vtbp[((size_t)(bh0 + h3) * 64 + dv) * SEQ + s0 + cc * 8] =
                        *(uint4*)outv;
                }
            }
        }
    } else if (EPI == 3) {                  // rmsnorm fold + silu(g)*u
#pragma unroll
        for (int mi = 0; mi < MI; ++mi)
#pragma unroll
            for (int r = 0; r < 4; ++r) {
                int row = m0 + wm + mi * 16 + lkg * 4 + r;
                float rr = rsqrtf(scale[row] * (1.0f / HIDD) + 1e-8f);
#pragma unroll
                for (int ni = 0; ni < 4; ni += 2) {
                    float g = acc[mi][ni][r] * rr, u = acc[mi][ni + 1][r] * rr;
                    float mv = (g / (1.0f + __expf(-g))) * u;
                    int j = (((n0 + wn + ni * 16) >> 5) << 4) + lr;
                    Cb[(size_t)row * 1024 + j] = (__bf16)mv;
                }
            }
    } else if (EPI == 4) {                  // bf16 out = f32 resid + acc*scale; Σh² -> Cf
        float ssq[MI][4];
#pragma unroll
        for (int mi = 0; mi < MI; ++mi)
#pragma unroll
            for (int r = 0; r < 4; ++r) ssq[mi][r] = 0.0f;
#pragma unroll
        for (int mi = 0; mi < MI; ++mi)
#pragma unroll
            for (int ni = 0; ni < NI; ++ni)
#pragma unroll
                for (int r = 0; r < 4; ++r) {
                    int row = m0 + wm + mi * 16 + lkg * 4 + r;
                    int col = n0 + wn + ni * 16 + lr;
                    size_t idx = (size_t)row * N + col;
                    __bf16 vb = (__bf16)(resid[idx] + acc[mi][ni][r] * scale[col]);
                    Cb[idx] = vb;
                    float vf = (float)vb;
                    ssq[mi][r] += vf * vf;
                }
        // reduce over the 16-lane row group, one atomic per row per block
#pragma unroll
        for (int mi = 0; mi < MI; ++mi)
#pragma unroll
            for (int r = 0; r < 4; ++r) {
                float ss = ssq[mi][r];
                ss += __shfl_xor(ss, 1);
                ss += __shfl_xor(ss, 2);
                ss += __shfl_xor(ss, 4);
                ss += __shfl_xor(ss, 8);
                if (lr == 0)
                    atomicAdd(&Cf[m0 + wm + mi * 16 + lkg * 4 + r], ss);
            }
    } else if (EPI == 5) {                  // f32 out = bf16 resid(Cb) + acc*scale
        const __bf16* rb = (const __bf16*)Cb;
#pragma unroll
        for (int mi = 0; mi < MI; ++mi)
#pragma unroll
            for (int ni = 0; ni < NI; ++ni)
#pragma unroll
                for (int r = 0; r < 4; ++r) {
                    int row = m0 + wm + mi * 16 + lkg * 4 + r;
                    int col = n0 + wn + ni * 16 + lr;
                    size_t idx = (size_t)row * N + col;
                    Cf[idx] = (float)rb[idx] + acc[mi][ni][r] * scale[col];
                }
    }
}

// ---------------- causal flash attention: dual wave-group, coalesced staging ----------------
__global__ __launch_bounds__(512, 4) void attn_k(const __bf16* __restrict__ qb,
                                                 const __bf16* __restrict__ kb,
                                                 const __bf16* __restrict__ vtb,
                                                 __bf16* __restrict__ outp) {
    __shared__ alignas(16) __bf16 KS[2][2][4096];
    __shared__ alignas(16) __bf16 VS[2][2][4096];
    int bh = blockIdx.x;
    int b = bh >> 4, h = bh & 15;
    int y = blockIdx.y;
    int qbA = y, qbB = 31 - y;
    int TA = y + 1;
    int tid = threadIdx.x;
    int grp = tid >> 8;
    int tg  = tid & 255;
    int lane = tid & 63, wg = tg >> 6;
    int lq = lane & 15, g = lane >> 4;
    size_t tokb = (size_t)b * SEQ;
    int qr0A = qbA * 64 + wg * 16, qr0B = qbB * 64 + wg * 16;

    bf16x8 ones8;
#pragma unroll
    for (int e = 0; e < 8; ++e) ones8[e] = (__bf16)1.0f;

    f32x4 oa[4] = {};
    f32x4 ol = {};

#define STAGE_K(kbn, kdst)                                                                         \
    {                                                                                              \
        _Pragma("unroll")                                                                          \
        for (int i = 0; i < 2; ++i) {                                                              \
            int c = i * 256 + tg;                                                                  \
            int kr = c >> 3, ch = c & 7;                                                           \
            gload16(&kb[((size_t)bh * SEQ + (kbn) * 64 + kr) * 64 + ((ch ^ (kr & 7)) << 3)],       \
                    (kdst) + c * 8);                                                               \
        }                                                                                          \
    }

#define STAGE_V(kbn, vdst)                                                                         \
    {                                                                                              \
        _Pragma("unroll")                                                                          \
        for (int i = 0; i < 2; ++i) {                                                              \
            int c = i * 256 + tg;                                                                  \
            int vr = c >> 3, ch = c & 7;                                                           \
            gload16(&vtb[((size_t)bh * 64 + vr) * SEQ + (kbn) * 64 + ((ch ^ (vr & 7)) << 3)],      \
                    (vdst) + c * 8);                                                               \
        }                                                                                          \
    }

#define QK_S(sc, aq, ksrc)                                                                         \
    {                                                                                              \
        __builtin_amdgcn_s_setprio(1);                                                             \
        _Pragma("unroll")                                                                          \
        for (int jt = 0; jt < 4; ++jt)                                                             \
            _Pragma("unroll")                                                                      \
            for (int ks = 0; ks < 2; ++ks) {                                                       \
                bf16x8 bk = *(const bf16x8*)&(ksrc)[(jt * 16 + lq) * 64 + (((ks * 4 + g) ^ (lq & 7)) << 3)]; \
                sc[jt] = __builtin_amdgcn_mfma_f32_16x16x32_bf16(bk, aq[ks], sc[jt], 0, 0, 0);     \
            }                                                                                      \
        __builtin_amdgcn_s_setprio(0);                                                             \
    }

#define MASK_S(sc, qr0_t, kb64)                                                                    \
    {                                                                                              \
        int qabs = (qr0_t) + lq;                                                                   \
        _Pragma("unroll")                                                                          \
        for (int jt = 0; jt < 4; ++jt)                                                             \
            _Pragma("unroll")                                                                      \
            for (int r = 0; r < 4; ++r) {                                                          \
                int key = (kb64) * 64 + jt * 16 + g * 4 + r;                                       \
                if (key > qabs) sc[jt][r] = -1e9f;                                                 \
            }                                                                                      \
    }

#define EXP_S(sc)                                                                                  \
    _Pragma("unroll")                                                                              \
    for (int jt = 0; jt < 4; ++jt)                                                                 \
        _Pragma("unroll")                                                                          \
        for (int r = 0; r < 4; ++r) sc[jt][r] = EXP2(sc[jt][r]);

#define PV_S(sc, vsrc)                                                                             \
    {                                                                                              \
        __builtin_amdgcn_s_setprio(1);                                                             \
        _Pragma("unroll")                                                                          \
        for (int ks2 = 0; ks2 < 2; ++ks2) {                                                        \
            bf16x8 pfv;                                                                            \
            _Pragma("unroll")                                                                      \
            for (int e = 0; e < 4; ++e) {                                                          \
                pfv[e]     = (__bf16)sc[2 * ks2][e];                                               \
                pfv[e + 4] = (__bf16)sc[2 * ks2 + 1][e];                                           \
            }                                                                                      \
            ol = __builtin_amdgcn_mfma_f32_16x16x32_bf16(ones8, pfv, ol, 0, 0, 0);                 \
            _Pragma("unroll")                                                                      \
            for (int dt = 0; dt < 4; ++dt) {                                                       \
                bf16x8 av = *(const bf16x8*)&(vsrc)[(dt * 16 + lq) * 64 + (((ks2 * 4 + g) ^ (lq & 7)) << 3)]; \
                oa[dt] = __builtin_amdgcn_mfma_f32_16x16x32_bf16(av, pfv, oa[dt], 0, 0, 0);        \
            }                                                                                      \
        }                                                                                          \
        __builtin_amdgcn_s_setprio(0);                                                             \
    }

    if (grp == 0) {
        bf16x8 aqB[2];
#pragma unroll
        for (int ks = 0; ks < 2; ++ks)
            aqB[ks] = *(const bf16x8*)&qb[(tokb + qr0B + lq) * 1024 + h * 64 + ks * 32 + g * 8];
        STAGE_K(0, KS[0][0]);
        STAGE_V(0, VS[0][0]);
        __syncthreads();
        for (int it = 0; it < 17; ++it) {
            int buf = it & 1;
            bool pf = it < 16;
            if (pf) {
                STAGE_K(it + 1, KS[0][buf ^ 1]);
                STAGE_V(it + 1, VS[0][buf ^ 1]);
            }
            f32x4 sc[4] = {};
            QK_S(sc, aqB, KS[0][buf]);
            if (it == qbB) MASK_S(sc, qr0B, it);
            EXP_S(sc);
            PV_S(sc, VS[0][buf]);
            __syncthreads();
        }
    } else {
        {
            bf16x8 aqA[2];
#pragma unroll
            for (int ks = 0; ks < 2; ++ks)
                aqA[ks] = *(const bf16x8*)&qb[(tokb + qr0A + lq) * 1024 + h * 64 + ks * 32 + g * 8];
            __syncthreads();
            for (int it = 0; it < TA; ++it) {
                int buf = it & 1;
                if (it == TA - 1) {
                    STAGE_K(17, KS[1][0]);
                    STAGE_V(17, VS[1][0]);
                }
                f32x4 sc[4] = {};
                QK_S(sc, aqA, KS[0][buf]);
                if (it == qbA) MASK_S(sc, qr0A, it);
                EXP_S(sc);
                PV_S(sc, VS[0][buf]);
                __syncthreads();
            }
        }
        {
            float inv = 1.0f / ol[0];
#pragma unroll
            for (int dt = 0; dt < 4; ++dt) {
                bf16x4 ov;
#pragma unroll
                for (int r = 0; r < 4; ++r) ov[r] = (__bf16)(oa[dt][r] * inv);
                *(bf16x4*)&outp[(tokb + qr0A + lq) * 1024 + h * 64 + dt * 16 + g * 4] = ov;
                oa[dt] = (f32x4){0.f, 0.f, 0.f, 0.f};
            }
            ol = (f32x4){0.f, 0.f, 0.f, 0.f};
        }
        {
            bf16x8 aqB[2];
#pragma unroll
            for (int ks = 0; ks < 2; ++ks)
                aqB[ks] = *(const bf16x8*)&qb[(tokb + qr0B + lq) * 1024 + h * 64 + ks * 32 + g * 8];
            int cnt = 16 - TA;
            for (int j = 0; j < cnt; ++j) {
                int buf = j & 1;
                if (j + 1 < cnt) {
                    STAGE_K(17 + j + 1, KS[1][buf ^ 1]);
                    STAGE_V(17 + j + 1, VS[1][buf ^ 1]);
                }
                f32x4 sc[4] = {};
                int kb64 = 17 + j;
                QK_S(sc, aqB, KS[1][buf]);
                if (kb64 == qbB) MASK_S(sc, qr0B, kb64);
                EXP_S(sc);
                PV_S(sc, VS[1][buf]);
                __syncthreads();
            }
        }
        __syncthreads();
    }

    float* mrg_oa = (float*)KS[1];
    float* mrg_ol = (float*)VS[1];
    if (grp == 1) {
#pragma unroll
        for (int dt = 0; dt < 4; ++dt)
#pragma unroll
            for (int r = 0; r < 4; ++r) mrg_oa[tg * 16 + dt * 4 + r] = oa[dt][r];
        mrg_ol[tg] = ol[0];
    }
    __syncthreads();
    if (grp == 0) {
        float l = ol[0] + mrg_ol[tg];
        float inv = 1.0f / l;
#pragma unroll
        for (int dt = 0; dt < 4; ++dt) {
            bf16x4 ov;
#pragma unroll
            for (int r = 0; r < 4; ++r)
                ov[r] = (__bf16)((oa[dt][r] + mrg_oa[tg * 16 + dt * 4 + r]) * inv);
            *(bf16x4*)&outp[(tokb + qr0B + lq) * 1024 + h * 64 + dt * 16 + g * 4] = ov;
        }
    }
#undef STAGE_K
#undef STAGE_V
#undef QK_S
#undef MASK_S
#undef EXP_S
#undef PV_S
}

// ---------------- launch ----------------
extern "C" void kernel_launch(void* const* d_in, const int* in_sizes, int n_in,
                              void* d_out, int out_size, void* d_ws, size_t ws_size,
                              hipStream_t stream) {
    const float* x       = (const float*)d_in[0];
    const float* cosv    = (const float*)d_in[1];
    const float* sinv    = (const float*)d_in[2];
    const float* wq      = (const float*)d_in[4];
    const float* wk      = (const float*)d_in[5];
    const float* wv      = (const float*)d_in[6];
    const float* wo      = (const float*)d_in[7];
    const float* wgate   = (const float*)d_in[8];
    const float* wup     = (const float*)d_in[9];
    const float* wdown   = (const float*)d_in[10];
    const float* norm1   = (const float*)d_in[11];
    const float* norm2   = (const float*)d_in[12];
    const float* ls_attn = (const float*)d_in[13];
    const float* ls_mlp  = (const float*)d_in[14];

    char* ws = (char*)d_ws;
    __bf16* wqkvT = (__bf16*)(ws + OFF_WQKVT);
    __bf16* woT   = (__bf16*)(ws + OFF_WOT);
    __bf16* wguT  = (__bf16*)(ws + OFF_WGUT);
    __bf16* wdT   = (__bf16*)(ws + OFF_WDT);
    __bf16* hb    = (__bf16*)(ws + OFF_HB);
    __bf16* qbuf  = (__bf16*)(ws + OFF_QB);
    __bf16* kbuf  = (__bf16*)(ws + OFF_KB);
    __bf16* vtbuf = (__bf16*)(ws + OFF_H2);     // vtb during attn
    __bf16* attnb = (__bf16*)(ws + OFF_ATTN);
    __bf16* h2b   = (__bf16*)(ws + OFF_H2);     // bf16 h2 after attn (vtb dead)
    float*  rvec  = (float*)(ws + OFF_RV);
    __bf16* mb    = (__bf16*)(ws + OFF_M);
    float*  outf  = (float*)d_out;

    prep_k<<<7680, 256, 0, stream>>>(
        wq, wk, wv, wo, wgate, wup, wdown, wqkvT, woT, wguT, wdT, x, norm1, norm2, hb, rvec);
    gemm_bt<1, 128, 128, 64><<<dim3(QKVN / 128, NTOK / 128), 256, 0, stream>>>(
        hb, wqkvT, NTOK, QKVN, 512, qbuf, nullptr, nullptr, nullptr, cosv, sinv, kbuf, vtbuf);
    attn_k<<<dim3(NB * NHEAD, 16), 512, 0, stream>>>(qbuf, kbuf, vtbuf, attnb);
    gemm_bt<4, 64, 64, 128><<<dim3(HIDD / 64, NTOK / 64), 256, 0, stream>>>(
        attnb, woT, NTOK, HIDD, 1024, h2b, rvec, x, ls_attn, nullptr, nullptr, nullptr, nullptr);
    gemm_bt<3, 128, 128, 64><<<dim3(GUN / 128, NTOK / 128), 256, 0, stream>>>(
        h2b, wguT, NTOK, GUN, 512, mb, nullptr, nullptr, rvec, nullptr, nullptr, nullptr, nullptr);
    gemm_bt<5, 64, 64, 128><<<dim3(HIDD / 64, NTOK / 64), 256, 0, stream>>>(
        mb, wdT, NTOK, HIDD, 1024, h2b, outf, nullptr, ls_mlp, nullptr, nullptr, nullptr, nullptr);
}